// Round 1
// baseline (2150.217 us; speedup 1.0000x reference)
//
#include <hip/hip_runtime.h>

#define N_NODES 100000
#define NPG     1000
#define B_GR    100
#define HDIM    128
#define E_EDGES 1600000

// ---------- helpers ----------
__device__ __forceinline__ float sigf(float x) { return 1.f / (1.f + __expf(-x)); }
__device__ __forceinline__ float tanh_fast(float x) { return 1.f - 2.f / (__expf(2.f * x) + 1.f); }

// ---------- CSR build ----------
__global__ void k_count(const int* __restrict__ dst, int* __restrict__ cnt) {
    int e = blockIdx.x * 256 + threadIdx.x;
    if (e < E_EDGES) atomicAdd(&cnt[dst[e]], 1);
}

__global__ void k_scan1(const int* __restrict__ cnt, int* __restrict__ row_ptr, int* __restrict__ bsum) {
    __shared__ int sd[256];
    int tid = threadIdx.x;
    int base = blockIdx.x * 1024 + tid * 4;
    int v[4];
#pragma unroll
    for (int j = 0; j < 4; ++j) {
        int i = base + j;
        v[j] = (i < N_NODES) ? cnt[i] : 0;
    }
    int s = v[0] + v[1] + v[2] + v[3];
    sd[tid] = s;
    __syncthreads();
    for (int off = 1; off < 256; off <<= 1) {
        int t = (tid >= off) ? sd[tid - off] : 0;
        __syncthreads();
        sd[tid] += t;
        __syncthreads();
    }
    int excl = sd[tid] - s;
    int run = excl;
#pragma unroll
    for (int j = 0; j < 4; ++j) {
        int i = base + j;
        run += v[j];
        if (i < N_NODES) row_ptr[1 + i] = run;
    }
    if (tid == 255) bsum[blockIdx.x] = sd[255];
}

__global__ void k_scan2(int* __restrict__ bsum, int nb) {
    if (threadIdx.x == 0 && blockIdx.x == 0) {
        int carry = 0;
        for (int b = 0; b < nb; ++b) {
            int t = bsum[b];
            bsum[b] = carry;
            carry += t;
        }
    }
}

__global__ void k_scan3(int* __restrict__ row_ptr, const int* __restrict__ bsum, int* __restrict__ cursor) {
    int i = blockIdx.x * 256 + threadIdx.x;
    if (i >= N_NODES) return;
    int incl = row_ptr[1 + i] + bsum[i >> 10];
    row_ptr[1 + i] = incl;
    if (i == 0) { row_ptr[0] = 0; cursor[0] = 0; }
    if (i + 1 < N_NODES) cursor[i + 1] = incl;
}

__global__ void k_fill(const int* __restrict__ src, const int* __restrict__ dst,
                       int* __restrict__ cursor, int* __restrict__ csr_src) {
    int e = blockIdx.x * 256 + threadIdx.x;
    if (e >= E_EDGES) return;
    int d = dst[e];
    int pos = atomicAdd(&cursor[d], 1);
    csr_src[pos] = src[e];
}

// ---------- conv layer 0 (CIN=3 -> 128), fused agg+transform+relu ----------
__global__ void k_conv0(const float* __restrict__ x, const int* __restrict__ rp, const int* __restrict__ csr,
                        const float* __restrict__ Ws, const float* __restrict__ Wn, const float* __restrict__ b,
                        float* __restrict__ out) {
    int n = blockIdx.x;
    int tid = threadIdx.x;
    __shared__ float sagg[3];
    if (tid < 3) sagg[tid] = 0.f;
    __syncthreads();
    int s0 = rp[n], s1 = rp[n + 1];
    int deg = s1 - s0;
    for (int j = tid; j < deg; j += 128) {
        int s = csr[s0 + j];
        atomicAdd(&sagg[0], x[s * 3 + 0]);
        atomicAdd(&sagg[1], x[s * 3 + 1]);
        atomicAdd(&sagg[2], x[s * 3 + 2]);
    }
    __syncthreads();
    float inv = 1.f / fmaxf((float)deg, 1.f);
    float a0 = sagg[0] * inv, a1 = sagg[1] * inv, a2 = sagg[2] * inv;
    float x0 = x[n * 3 + 0], x1 = x[n * 3 + 1], x2 = x[n * 3 + 2];
    float acc = b[tid]
        + x0 * Ws[0 * 128 + tid] + x1 * Ws[1 * 128 + tid] + x2 * Ws[2 * 128 + tid]
        + a0 * Wn[0 * 128 + tid] + a1 * Wn[1 * 128 + tid] + a2 * Wn[2 * 128 + tid];
    out[n * 128 + tid] = fmaxf(acc, 0.f);
}

// ---------- conv layer 1 neighbor aggregation: B[n,:] = mean_nbr A[src,:] ----------
__global__ void k_agg(const float* __restrict__ hin, const int* __restrict__ rp, const int* __restrict__ csr,
                      float* __restrict__ out) {
    int n = blockIdx.x;
    int tid = threadIdx.x;
    __shared__ int sidx[128];
    int s0 = rp[n], s1 = rp[n + 1];
    int deg = s1 - s0;
    float acc = 0.f;
    for (int base = 0; base < deg; base += 128) {
        int m = min(128, deg - base);
        if (tid < m) sidx[tid] = csr[s0 + base + tid];
        __syncthreads();
        for (int j = 0; j < m; ++j) acc += hin[sidx[j] * 128 + tid];
        __syncthreads();
    }
    out[n * 128 + tid] = acc / fmaxf((float)deg, 1.f);
}

// ---------- conv layer 1 transform: B <- relu(A@Wself + B@Wnbr + bias), in place ----------
__global__ __launch_bounds__(256)
void k_conv1mm(const float* __restrict__ A, float* __restrict__ B,
               const float* __restrict__ Wself, const float* __restrict__ Wnbr,
               const float* __restrict__ bias) {
    __shared__ float As[64 * 64];
    __shared__ float Wls[64 * 128];
    int tid = threadIdx.x;
    int r0 = blockIdx.x * 64;
    int tx = tid & 31, ty = tid >> 5;
    float acc[8][4];
#pragma unroll
    for (int r = 0; r < 8; ++r)
#pragma unroll
        for (int j = 0; j < 4; ++j) acc[r][j] = 0.f;

    for (int chunk = 0; chunk < 4; ++chunk) {
        const float* Asrc = (chunk < 2) ? A : B;
        const float* Wsrc = (chunk < 2) ? Wself : Wnbr;
        int k0 = (chunk & 1) * 64;
        // stage A tile 64x64
#pragma unroll
        for (int i = 0; i < 4; ++i) {
            int e = tid + 256 * i;
            int row = e >> 4, c4 = e & 15;
            int grow = r0 + row;
            float4 v = make_float4(0.f, 0.f, 0.f, 0.f);
            if (grow < N_NODES) v = *(const float4*)&Asrc[grow * 128 + k0 + c4 * 4];
            *(float4*)&As[row * 64 + c4 * 4] = v;
        }
        // stage W tile 64x128
#pragma unroll
        for (int i = 0; i < 8; ++i) {
            int e = tid + 256 * i;
            int row = e >> 5, c4 = e & 31;
            *(float4*)&Wls[row * 128 + c4 * 4] = *(const float4*)&Wsrc[(k0 + row) * 128 + c4 * 4];
        }
        __syncthreads();
#pragma unroll 4
        for (int kk = 0; kk < 64; ++kk) {
            float4 w = *(const float4*)&Wls[kk * 128 + tx * 4];
#pragma unroll
            for (int r = 0; r < 8; ++r) {
                float a = As[(ty + 8 * r) * 64 + kk];
                acc[r][0] += a * w.x; acc[r][1] += a * w.y;
                acc[r][2] += a * w.z; acc[r][3] += a * w.w;
            }
        }
        __syncthreads();
    }
    float4 bb = *(const float4*)&bias[tx * 4];
#pragma unroll
    for (int r = 0; r < 8; ++r) {
        int grow = r0 + ty + 8 * r;
        if (grow < N_NODES) {
            float4 v;
            v.x = fmaxf(acc[r][0] + bb.x, 0.f);
            v.y = fmaxf(acc[r][1] + bb.y, 0.f);
            v.z = fmaxf(acc[r][2] + bb.z, 0.f);
            v.w = fmaxf(acc[r][3] + bb.w, 0.f);
            *(float4*)&B[grow * 128 + tx * 4] = v;
        }
    }
}

// ---------- LSTM weight prep: WT[l][k(0..255)][c(0..511)], k<128 = Wih^T, k>=128 = Whh^T ----------
__global__ void k_prep(const float* __restrict__ Wih0, const float* __restrict__ Whh0,
                       const float* __restrict__ Wih1, const float* __restrict__ Whh1,
                       float* __restrict__ WT) {
    int idx = blockIdx.x * 256 + threadIdx.x; // 0..262143
    int l = idx >> 17;
    int rem = idx & 131071;
    int kk = rem >> 9;
    int c = rem & 511;
    const float* Wi = l ? Wih1 : Wih0;
    const float* Wh = l ? Whh1 : Whh0;
    float v = (kk < 128) ? Wi[c * 128 + kk] : Wh[c * 128 + (kk - 128)];
    WT[idx] = v;
}

__global__ void k_bsum(const float* __restrict__ bih0, const float* __restrict__ bhh0,
                       const float* __restrict__ bih1, const float* __restrict__ bhh1,
                       float* __restrict__ bs) {
    int i = blockIdx.x * 256 + threadIdx.x; // 0..1023
    int l = i >> 9, c = i & 511;
    bs[i] = l ? (bih1[c] + bhh1[c]) : (bih0[c] + bhh0[c]);
}

// ---------- persistent 2-layer LSTM, 4 rows per block, fused pooling ----------
__device__ __forceinline__ void gemm_step(const float* inT, const float* hT,
                                          const float* __restrict__ WT, const float* __restrict__ bs,
                                          float* g, int tid) {
    float a00 = 0, a01 = 0, a02 = 0, a03 = 0, a10 = 0, a11 = 0, a12 = 0, a13 = 0;
#pragma unroll 8
    for (int k = 0; k < 128; ++k) {
        float4 a = *(const float4*)&inT[k * 4];
        float w0 = WT[k * 512 + tid];
        float w1 = WT[k * 512 + 256 + tid];
        a00 += a.x * w0; a01 += a.y * w0; a02 += a.z * w0; a03 += a.w * w0;
        a10 += a.x * w1; a11 += a.y * w1; a12 += a.z * w1; a13 += a.w * w1;
    }
#pragma unroll 8
    for (int k = 0; k < 128; ++k) {
        float4 a = *(const float4*)&hT[k * 4];
        float w0 = WT[(128 + k) * 512 + tid];
        float w1 = WT[(128 + k) * 512 + 256 + tid];
        a00 += a.x * w0; a01 += a.y * w0; a02 += a.z * w0; a03 += a.w * w0;
        a10 += a.x * w1; a11 += a.y * w1; a12 += a.z * w1; a13 += a.w * w1;
    }
    float b0v = bs[tid], b1v = bs[tid + 256];
    g[0 * 512 + tid] = a00 + b0v; g[1 * 512 + tid] = a01 + b0v;
    g[2 * 512 + tid] = a02 + b0v; g[3 * 512 + tid] = a03 + b0v;
    g[0 * 512 + 256 + tid] = a10 + b1v; g[1 * 512 + 256 + tid] = a11 + b1v;
    g[2 * 512 + 256 + tid] = a12 + b1v; g[3 * 512 + 256 + tid] = a13 + b1v;
}

__device__ __forceinline__ void gate_step(const float* g, float& cA, float& cB, float* hT,
                                          int rA, int dA, float* pool) {
    float i1 = g[rA * 512 + dA], f1 = g[rA * 512 + 128 + dA];
    float gg1 = g[rA * 512 + 256 + dA], o1 = g[rA * 512 + 384 + dA];
    float c1 = sigf(f1) * cA + sigf(i1) * tanh_fast(gg1);
    float h1 = sigf(o1) * tanh_fast(c1);
    cA = c1;
    hT[dA * 4 + rA] = h1;
    int r2 = rA + 2;
    float i2 = g[r2 * 512 + dA], f2 = g[r2 * 512 + 128 + dA];
    float gg2 = g[r2 * 512 + 256 + dA], o2 = g[r2 * 512 + 384 + dA];
    float c2 = sigf(f2) * cB + sigf(i2) * tanh_fast(gg2);
    float h2 = sigf(o2) * tanh_fast(c2);
    cB = c2;
    hT[dA * 4 + r2] = h2;
    if (pool) atomicAdd(&pool[dA], h1 + h2);
}

__global__ __launch_bounds__(256)
void k_lstm(const float* __restrict__ X, const float* __restrict__ WT, const float* __restrict__ bs,
            float* __restrict__ pooled) {
    __shared__ float xsT[128 * 4];
    __shared__ float h0T[128 * 4];
    __shared__ float h1T[128 * 4];
    __shared__ float g[4 * 512];
    int tid = threadIdx.x;
    int n0 = blockIdx.x * 4;
    h0T[tid] = 0.f; h0T[tid + 256] = 0.f;
    h1T[tid] = 0.f; h1T[tid + 256] = 0.f;
    float cA0 = 0, cB0 = 0, cA1 = 0, cB1 = 0;
    const int dA = tid & 127, rA = tid >> 7;
    __syncthreads();
    for (int t = 0; t < 100; ++t) {
        {
            int e = tid;
#pragma unroll
            for (int j = 0; j < 2; ++j, e += 256) {
                int r = e >> 7, k = e & 127;
                xsT[k * 4 + r] = X[(t * 1000 + n0 + r) * 128 + k];
            }
        }
        __syncthreads();
        gemm_step(xsT, h0T, WT, bs, g, tid);
        __syncthreads();
        gate_step(g, cA0, cB0, h0T, rA, dA, nullptr);
        __syncthreads();
        gemm_step(h0T, h1T, WT + 131072, bs + 512, g, tid);
        __syncthreads();
        gate_step(g, cA1, cB1, h1T, rA, dA, pooled + t * 128);
        __syncthreads();
    }
}

// ---------- head: logits + log_softmax ----------
__global__ void k_head(const float* __restrict__ pooled, const float* __restrict__ Wout,
                       const float* __restrict__ bout, float* __restrict__ out) {
    int gi = threadIdx.x;
    if (gi >= B_GR) return;
    float l0 = bout[0], l1 = bout[1];
    for (int d = 0; d < 128; ++d) {
        float p = pooled[gi * 128 + d] / 1000.0f;
        l0 += p * Wout[d * 2 + 0];
        l1 += p * Wout[d * 2 + 1];
    }
    float m = fmaxf(l0, l1);
    float lse = m + logf(__expf(l0 - m) + __expf(l1 - m));
    out[gi * 2 + 0] = l0 - lse;
    out[gi * 2 + 1] = l1 - lse;
}

// ---------- launch ----------
extern "C" void kernel_launch(void* const* d_in, const int* in_sizes, int n_in,
                              void* d_out, int out_size, void* d_ws, size_t ws_size,
                              hipStream_t stream) {
    const float* x    = (const float*)d_in[0];
    const int*   ei   = (const int*)d_in[1];
    const int*   srcI = ei;
    const int*   dstI = ei + E_EDGES;
    const float* Ws0  = (const float*)d_in[3];
    const float* Wn0  = (const float*)d_in[4];
    const float* b0   = (const float*)d_in[5];
    const float* Ws1  = (const float*)d_in[6];
    const float* Wn1  = (const float*)d_in[7];
    const float* b1   = (const float*)d_in[8];
    const float* Wih0 = (const float*)d_in[9];
    const float* Whh0 = (const float*)d_in[10];
    const float* bih0 = (const float*)d_in[11];
    const float* bhh0 = (const float*)d_in[12];
    const float* Wih1 = (const float*)d_in[13];
    const float* Whh1 = (const float*)d_in[14];
    const float* bih1 = (const float*)d_in[15];
    const float* bhh1 = (const float*)d_in[16];
    const float* Wout = (const float*)d_in[17];
    const float* bout = (const float*)d_in[18];
    float* out = (float*)d_out;

    char* ws = (char*)d_ws;
    int*   row_ptr = (int*)(ws + 0);            // (N+1) ints, padded region 400128 B
    int*   cursor  = (int*)(ws + 400128);       // N ints           -> 800128
    int*   csr_src = (int*)(ws + 800128);       // E ints           -> 7200128
    int*   bsum    = (int*)(ws + 7200128);      // 128 ints         -> 7200640
    float* bufA    = (float*)(ws + 7200640);    // N*128 f32        -> 58400640
    float* bufB    = (float*)(ws + 58400640);   // N*128 f32        -> 109600640
    float* WT      = (float*)(ws + 109600640);  // 2*256*512 f32    -> 110649216
    float* bsB     = (float*)(ws + 110649216);  // 1024 f32         -> 110653312
    float* pooled  = (float*)(ws + 110653312);  // 100*128 f32      -> 110704512

    hipMemsetAsync(cursor, 0, N_NODES * sizeof(int), stream);
    hipMemsetAsync(pooled, 0, B_GR * 128 * sizeof(float), stream);

    k_count<<<E_EDGES / 256, 256, 0, stream>>>(dstI, cursor);
    k_scan1<<<98, 256, 0, stream>>>(cursor, row_ptr, bsum);
    k_scan2<<<1, 64, 0, stream>>>(bsum, 98);
    k_scan3<<<(N_NODES + 255) / 256, 256, 0, stream>>>(row_ptr, bsum, cursor);
    k_fill<<<E_EDGES / 256, 256, 0, stream>>>(srcI, dstI, cursor, csr_src);

    k_conv0<<<N_NODES, 128, 0, stream>>>(x, row_ptr, csr_src, Ws0, Wn0, b0, bufA);
    k_agg<<<N_NODES, 128, 0, stream>>>(bufA, row_ptr, csr_src, bufB);
    k_conv1mm<<<(N_NODES + 63) / 64, 256, 0, stream>>>(bufA, bufB, Ws1, Wn1, b1);

    k_prep<<<1024, 256, 0, stream>>>(Wih0, Whh0, Wih1, Whh1, WT);
    k_bsum<<<4, 256, 0, stream>>>(bih0, bhh0, bih1, bhh1, bsB);

    k_lstm<<<250, 256, 0, stream>>>(bufB, WT, bsB, pooled);

    k_head<<<1, 128, 0, stream>>>(pooled, Wout, bout, out);
}

// Round 2
// 1007.130 us; speedup vs baseline: 2.1350x; 2.1350x over previous
//
#include <hip/hip_runtime.h>

#define N_NODES 100000
#define NPG     1000
#define B_GR    100
#define HDIM    128
#define E_EDGES 1600000

typedef __attribute__((ext_vector_type(8))) short bf16x8;
typedef __attribute__((ext_vector_type(4))) float f32x4;
typedef unsigned long long u64;

// ---------- helpers ----------
__device__ __forceinline__ float sigf(float x) { return 1.f / (1.f + __expf(-x)); }
__device__ __forceinline__ float tanh_fast(float x) { return 1.f - 2.f / (__expf(2.f * x) + 1.f); }
__device__ __forceinline__ unsigned short f2bf(float f) {
    unsigned u = __float_as_uint(f);
    unsigned r = (u + 0x7fffu + ((u >> 16) & 1u)) >> 16;
    return (unsigned short)r;
}

// ---------- CSR build ----------
__global__ void k_count(const int* __restrict__ dst, int* __restrict__ cnt) {
    int e = blockIdx.x * 256 + threadIdx.x;
    if (e < E_EDGES) atomicAdd(&cnt[dst[e]], 1);
}

__global__ void k_scan1(const int* __restrict__ cnt, int* __restrict__ row_ptr, int* __restrict__ bsum) {
    __shared__ int sd[256];
    int tid = threadIdx.x;
    int base = blockIdx.x * 1024 + tid * 4;
    int v[4];
#pragma unroll
    for (int j = 0; j < 4; ++j) {
        int i = base + j;
        v[j] = (i < N_NODES) ? cnt[i] : 0;
    }
    int s = v[0] + v[1] + v[2] + v[3];
    sd[tid] = s;
    __syncthreads();
    for (int off = 1; off < 256; off <<= 1) {
        int t = (tid >= off) ? sd[tid - off] : 0;
        __syncthreads();
        sd[tid] += t;
        __syncthreads();
    }
    int excl = sd[tid] - s;
    int run = excl;
#pragma unroll
    for (int j = 0; j < 4; ++j) {
        int i = base + j;
        run += v[j];
        if (i < N_NODES) row_ptr[1 + i] = run;
    }
    if (tid == 255) bsum[blockIdx.x] = sd[255];
}

__global__ void k_scan2(int* __restrict__ bsum, int nb) {
    if (threadIdx.x == 0 && blockIdx.x == 0) {
        int carry = 0;
        for (int b = 0; b < nb; ++b) {
            int t = bsum[b];
            bsum[b] = carry;
            carry += t;
        }
    }
}

__global__ void k_scan3(int* __restrict__ row_ptr, const int* __restrict__ bsum, int* __restrict__ cursor) {
    int i = blockIdx.x * 256 + threadIdx.x;
    if (i >= N_NODES) return;
    int incl = row_ptr[1 + i] + bsum[i >> 10];
    row_ptr[1 + i] = incl;
    if (i == 0) { row_ptr[0] = 0; cursor[0] = 0; }
    if (i + 1 < N_NODES) cursor[i + 1] = incl;
}

__global__ void k_fill(const int* __restrict__ src, const int* __restrict__ dst,
                       int* __restrict__ cursor, int* __restrict__ csr_src) {
    int e = blockIdx.x * 256 + threadIdx.x;
    if (e >= E_EDGES) return;
    int d = dst[e];
    int pos = atomicAdd(&cursor[d], 1);
    csr_src[pos] = src[e];
}

// ---------- conv layer 0 (CIN=3 -> 128), fused agg+transform+relu ----------
__global__ void k_conv0(const float* __restrict__ x, const int* __restrict__ rp, const int* __restrict__ csr,
                        const float* __restrict__ Ws, const float* __restrict__ Wn, const float* __restrict__ b,
                        float* __restrict__ out) {
    int n = blockIdx.x;
    int tid = threadIdx.x;
    __shared__ float sagg[3];
    if (tid < 3) sagg[tid] = 0.f;
    __syncthreads();
    int s0 = rp[n], s1 = rp[n + 1];
    int deg = s1 - s0;
    for (int j = tid; j < deg; j += 128) {
        int s = csr[s0 + j];
        atomicAdd(&sagg[0], x[s * 3 + 0]);
        atomicAdd(&sagg[1], x[s * 3 + 1]);
        atomicAdd(&sagg[2], x[s * 3 + 2]);
    }
    __syncthreads();
    float inv = 1.f / fmaxf((float)deg, 1.f);
    float a0 = sagg[0] * inv, a1 = sagg[1] * inv, a2 = sagg[2] * inv;
    float x0 = x[n * 3 + 0], x1 = x[n * 3 + 1], x2 = x[n * 3 + 2];
    float acc = b[tid]
        + x0 * Ws[0 * 128 + tid] + x1 * Ws[1 * 128 + tid] + x2 * Ws[2 * 128 + tid]
        + a0 * Wn[0 * 128 + tid] + a1 * Wn[1 * 128 + tid] + a2 * Wn[2 * 128 + tid];
    out[n * 128 + tid] = fmaxf(acc, 0.f);
}

// ---------- conv layer 1 neighbor aggregation ----------
__global__ void k_agg(const float* __restrict__ hin, const int* __restrict__ rp, const int* __restrict__ csr,
                      float* __restrict__ out) {
    int n = blockIdx.x;
    int tid = threadIdx.x;
    __shared__ int sidx[128];
    int s0 = rp[n], s1 = rp[n + 1];
    int deg = s1 - s0;
    float acc = 0.f;
    for (int base = 0; base < deg; base += 128) {
        int m = min(128, deg - base);
        if (tid < m) sidx[tid] = csr[s0 + base + tid];
        __syncthreads();
        for (int j = 0; j < m; ++j) acc += hin[sidx[j] * 128 + tid];
        __syncthreads();
    }
    out[n * 128 + tid] = acc / fmaxf((float)deg, 1.f);
}

// ---------- conv layer 1 transform: B <- relu(A@Wself + B@Wnbr + bias), in place ----------
__global__ __launch_bounds__(256)
void k_conv1mm(const float* __restrict__ A, float* __restrict__ B,
               const float* __restrict__ Wself, const float* __restrict__ Wnbr,
               const float* __restrict__ bias) {
    __shared__ float As[64 * 64];
    __shared__ float Wls[64 * 128];
    int tid = threadIdx.x;
    int r0 = blockIdx.x * 64;
    int tx = tid & 31, ty = tid >> 5;
    float acc[8][4];
#pragma unroll
    for (int r = 0; r < 8; ++r)
#pragma unroll
        for (int j = 0; j < 4; ++j) acc[r][j] = 0.f;

    for (int chunk = 0; chunk < 4; ++chunk) {
        const float* Asrc = (chunk < 2) ? A : B;
        const float* Wsrc = (chunk < 2) ? Wself : Wnbr;
        int k0 = (chunk & 1) * 64;
#pragma unroll
        for (int i = 0; i < 4; ++i) {
            int e = tid + 256 * i;
            int row = e >> 4, c4 = e & 15;
            int grow = r0 + row;
            float4 v = make_float4(0.f, 0.f, 0.f, 0.f);
            if (grow < N_NODES) v = *(const float4*)&Asrc[grow * 128 + k0 + c4 * 4];
            *(float4*)&As[row * 64 + c4 * 4] = v;
        }
#pragma unroll
        for (int i = 0; i < 8; ++i) {
            int e = tid + 256 * i;
            int row = e >> 5, c4 = e & 31;
            *(float4*)&Wls[row * 128 + c4 * 4] = *(const float4*)&Wsrc[(k0 + row) * 128 + c4 * 4];
        }
        __syncthreads();
#pragma unroll 4
        for (int kk = 0; kk < 64; ++kk) {
            float4 w = *(const float4*)&Wls[kk * 128 + tx * 4];
#pragma unroll
            for (int r = 0; r < 8; ++r) {
                float a = As[(ty + 8 * r) * 64 + kk];
                acc[r][0] += a * w.x; acc[r][1] += a * w.y;
                acc[r][2] += a * w.z; acc[r][3] += a * w.w;
            }
        }
        __syncthreads();
    }
    float4 bb = *(const float4*)&bias[tx * 4];
#pragma unroll
    for (int r = 0; r < 8; ++r) {
        int grow = r0 + ty + 8 * r;
        if (grow < N_NODES) {
            float4 v;
            v.x = fmaxf(acc[r][0] + bb.x, 0.f);
            v.y = fmaxf(acc[r][1] + bb.y, 0.f);
            v.z = fmaxf(acc[r][2] + bb.z, 0.f);
            v.w = fmaxf(acc[r][3] + bb.w, 0.f);
            *(float4*)&B[grow * 128 + tx * 4] = v;
        }
    }
}

// ---------- LSTM weight prep: pack B-fragments in MFMA order, bf16 ----------
// Layout: frag (layer l, wave w, ktile kt, gate gt): 64 lanes x 8 bf16.
// B element for lane ln, j: col d = 16w + (ln&15); k = kt*32 + (ln>>4)*8 + j;
// weight row = gt*128 + d; val = k<128 ? Wih[row][k] : Whh[row][k-128].
__global__ void k_prepf(const float* __restrict__ Wih0, const float* __restrict__ Whh0,
                        const float* __restrict__ Wih1, const float* __restrict__ Whh1,
                        unsigned short* __restrict__ WTf) {
    int idx = blockIdx.x * 256 + threadIdx.x;   // 0..32767
    int lane = idx & 63;
    int gt = (idx >> 6) & 3;
    int kt = (idx >> 8) & 7;
    int w  = (idx >> 11) & 7;
    int l  = idx >> 14;
    int d = 16 * w + (lane & 15);
    int k0 = kt * 32 + (lane >> 4) * 8;
    int wrow = gt * 128 + d;
    const float* Wi = l ? Wih1 : Wih0;
    const float* Wh = l ? Whh1 : Whh0;
    const float* srcp = (k0 < 128) ? (Wi + wrow * 128 + k0) : (Wh + wrow * 128 + (k0 - 128));
    unsigned short o[8];
#pragma unroll
    for (int j = 0; j < 8; ++j) o[j] = f2bf(srcp[j]);
    u64 lo = (u64)o[0] | ((u64)o[1] << 16) | ((u64)o[2] << 32) | ((u64)o[3] << 48);
    u64 hi = (u64)o[4] | ((u64)o[5] << 16) | ((u64)o[6] << 32) | ((u64)o[7] << 48);
    u64* dst = (u64*)(WTf + (size_t)idx * 8);
    dst[0] = lo; dst[1] = hi;
}

__global__ void k_bsum(const float* __restrict__ bih0, const float* __restrict__ bhh0,
                       const float* __restrict__ bih1, const float* __restrict__ bhh1,
                       float* __restrict__ bs) {
    int i = blockIdx.x * 256 + threadIdx.x; // 0..1023
    int l = i >> 9, c = i & 511;
    bs[i] = l ? (bih1[c] + bhh1[c]) : (bih0[c] + bhh0[c]);
}

// ---------- single-layer persistent LSTM with MFMA, weights in registers ----------
// 63 blocks x 16 rows, 512 threads (8 waves). Wave w owns gate-aligned col quad
// {16w, 128+16w, 256+16w, 384+16w}: gates computed fully in-register.
// h tile (16x128 bf16) lives in LDS in A-fragment order -> linear ds_read_b128.
__global__ __launch_bounds__(512, 2)
void k_lstm_layer(const float* __restrict__ X32,          // mode 0 input: fp32 [T*1000][128]
                  const unsigned short* __restrict__ Xf,  // mode 1 input: frag-order bf16
                  const unsigned short* __restrict__ WTf, // this layer's packed frags
                  const float* __restrict__ bsL,          // 512 bias sums
                  unsigned short* __restrict__ Hf_out,    // mode 0 output (frag-order)
                  float* __restrict__ pooled,             // mode 1 output
                  int mode) {
    __shared__ __align__(16) unsigned short xs[2048];  // 16 rows x 128 k, frag order
    __shared__ __align__(16) unsigned short hs[2048];
    int tid = threadIdx.x;
    int l = tid & 63;
    int w = tid >> 6;
    int rb = blockIdx.x;
    int n0 = rb * 16;
    int nreal = (n0 + 16 <= NPG) ? 16 : (NPG - n0);   // rows of this block within a graph

    // preload this wave's 32 B-fragments (128 VGPRs)
    bf16x8 Bw[8][4];
    const bf16x8* Wv = (const bf16x8*)WTf;
#pragma unroll
    for (int kt = 0; kt < 8; ++kt)
#pragma unroll
        for (int gt = 0; gt < 4; ++gt)
            Bw[kt][gt] = Wv[((w * 8 + kt) * 4 + gt) * 64 + l];

    int d = (w << 4) | (l & 15);
    float bi = bsL[d], bf_ = bsL[128 + d], bg = bsL[256 + d], bo = bsL[384 + d];
    float cst0 = 0.f, cst1 = 0.f, cst2 = 0.f, cst3 = 0.f;

    // h-write position (halfword index into frag-order tile), + reg*8 per reg
    int ktp = d >> 5, oct = (d >> 3) & 3, boff = d & 7;
    int hbase = ktp * 512 + ((l >> 4) * 4 + 16 * oct) * 8 + boff;

    ((u64*)hs)[tid] = 0ull;
    __syncthreads();

    for (int t = 0; t < 100; ++t) {
        // ---- stage x_t into frag-order LDS ----
        if (mode == 0) {
            int r = tid & 15, g = tid >> 4;        // g: 0..31, covers k = 4g..4g+3
            int row = n0 + r;
            f32x4 v = {0.f, 0.f, 0.f, 0.f};
            if (row < NPG) v = *(const f32x4*)(X32 + (size_t)(t * NPG + row) * 128 + g * 4);
            unsigned short h0 = f2bf(v.x), h1 = f2bf(v.y), h2 = f2bf(v.z), h3 = f2bf(v.w);
            u64 pk = (u64)h0 | ((u64)h1 << 16) | ((u64)h2 << 32) | ((u64)h3 << 48);
            int dd = g * 4;
            int hw = (dd >> 5) * 512 + (r + 16 * ((dd >> 3) & 3)) * 8 + (dd & 7);
            *(u64*)(xs + hw) = pk;
        } else {
            const u64* srcp = (const u64*)(Xf + (size_t)(t * 63 + rb) * 2048);
            ((u64*)xs)[tid] = srcp[tid];
        }
        __syncthreads();   // xs ready; hs writes from t-1 visible

        // ---- MFMA: acc[gt] = [x_t | h] @ W  (K=256) ----
        f32x4 acc[4];
#pragma unroll
        for (int gt = 0; gt < 4; ++gt) acc[gt] = (f32x4){0.f, 0.f, 0.f, 0.f};
#pragma unroll
        for (int kt = 0; kt < 8; ++kt) {
            const unsigned short* base = (kt < 4) ? xs : hs;
            bf16x8 a = *(const bf16x8*)(base + (kt & 3) * 512 + l * 8);
            acc[0] = __builtin_amdgcn_mfma_f32_16x16x32_bf16(a, Bw[kt][0], acc[0], 0, 0, 0);
            acc[1] = __builtin_amdgcn_mfma_f32_16x16x32_bf16(a, Bw[kt][1], acc[1], 0, 0, 0);
            acc[2] = __builtin_amdgcn_mfma_f32_16x16x32_bf16(a, Bw[kt][2], acc[2], 0, 0, 0);
            acc[3] = __builtin_amdgcn_mfma_f32_16x16x32_bf16(a, Bw[kt][3], acc[3], 0, 0, 0);
        }
        __syncthreads();   // all hs reads done before overwrite

        // ---- gates in-register; write h to LDS (+ global / pooling) ----
        float hsum = 0.f;
#pragma unroll
        for (int reg = 0; reg < 4; ++reg) {
            float gi = acc[0][reg] + bi;
            float gf = acc[1][reg] + bf_;
            float gg = acc[2][reg] + bg;
            float go = acc[3][reg] + bo;
            float cprev = (reg == 0) ? cst0 : (reg == 1) ? cst1 : (reg == 2) ? cst2 : cst3;
            float c = sigf(gf) * cprev + sigf(gi) * tanh_fast(gg);
            if (reg == 0) cst0 = c; else if (reg == 1) cst1 = c; else if (reg == 2) cst2 = c; else cst3 = c;
            float h = sigf(go) * tanh_fast(c);
            unsigned short hb = f2bf(h);
            hs[hbase + reg * 8] = hb;
            if (mode == 0) {
                Hf_out[(size_t)(t * 63 + rb) * 2048 + hbase + reg * 8] = hb;
            } else {
                int row = (l >> 4) * 4 + reg;
                if (row < nreal) hsum += h;
            }
        }
        if (mode == 1) {
            hsum += __shfl_xor(hsum, 16);
            hsum += __shfl_xor(hsum, 32);
            if ((l >> 4) == 0) atomicAdd(&pooled[t * 128 + d], hsum);
        }
        __syncthreads();   // hs writes land before next iteration's reads
    }
}

// ---------- head: logits + log_softmax ----------
__global__ void k_head(const float* __restrict__ pooled, const float* __restrict__ Wout,
                       const float* __restrict__ bout, float* __restrict__ out) {
    int gi = threadIdx.x;
    if (gi >= B_GR) return;
    float l0 = bout[0], l1 = bout[1];
    for (int d = 0; d < 128; ++d) {
        float p = pooled[gi * 128 + d] / 1000.0f;
        l0 += p * Wout[d * 2 + 0];
        l1 += p * Wout[d * 2 + 1];
    }
    float m = fmaxf(l0, l1);
    float lse = m + logf(__expf(l0 - m) + __expf(l1 - m));
    out[gi * 2 + 0] = l0 - lse;
    out[gi * 2 + 1] = l1 - lse;
}

// ---------- launch ----------
extern "C" void kernel_launch(void* const* d_in, const int* in_sizes, int n_in,
                              void* d_out, int out_size, void* d_ws, size_t ws_size,
                              hipStream_t stream) {
    const float* x    = (const float*)d_in[0];
    const int*   ei   = (const int*)d_in[1];
    const int*   srcI = ei;
    const int*   dstI = ei + E_EDGES;
    const float* Ws0  = (const float*)d_in[3];
    const float* Wn0  = (const float*)d_in[4];
    const float* b0   = (const float*)d_in[5];
    const float* Ws1  = (const float*)d_in[6];
    const float* Wn1  = (const float*)d_in[7];
    const float* b1   = (const float*)d_in[8];
    const float* Wih0 = (const float*)d_in[9];
    const float* Whh0 = (const float*)d_in[10];
    const float* bih0 = (const float*)d_in[11];
    const float* bhh0 = (const float*)d_in[12];
    const float* Wih1 = (const float*)d_in[13];
    const float* Whh1 = (const float*)d_in[14];
    const float* bih1 = (const float*)d_in[15];
    const float* bhh1 = (const float*)d_in[16];
    const float* Wout = (const float*)d_in[17];
    const float* bout = (const float*)d_in[18];
    float* out = (float*)d_out;

    char* ws = (char*)d_ws;
    int*   row_ptr = (int*)(ws + 0);            // (N+1) ints, padded region 400128 B
    int*   cursor  = (int*)(ws + 400128);       // N ints           -> 800128
    int*   csr_src = (int*)(ws + 800128);       // E ints           -> 7200128
    int*   bsum    = (int*)(ws + 7200128);      // 128 ints         -> 7200640
    float* bufA    = (float*)(ws + 7200640);    // N*128 f32        -> 58400640  (reused as H0f)
    float* bufB    = (float*)(ws + 58400640);   // N*128 f32        -> 109600640
    unsigned short* WTf = (unsigned short*)(ws + 109600640);  // 2*256KB bf16 -> 110124928 (1MB reserved)
    float* bsB     = (float*)(ws + 110649216);  // 1024 f32         -> 110653312
    float* pooled  = (float*)(ws + 110653312);  // 100*128 f32      -> 110704512

    unsigned short* H0f = (unsigned short*)bufA;  // 100*63*2048 bf16 = 25.8MB, fits in bufA

    hipMemsetAsync(cursor, 0, N_NODES * sizeof(int), stream);
    hipMemsetAsync(pooled, 0, B_GR * 128 * sizeof(float), stream);

    k_count<<<E_EDGES / 256, 256, 0, stream>>>(dstI, cursor);
    k_scan1<<<98, 256, 0, stream>>>(cursor, row_ptr, bsum);
    k_scan2<<<1, 64, 0, stream>>>(bsum, 98);
    k_scan3<<<(N_NODES + 255) / 256, 256, 0, stream>>>(row_ptr, bsum, cursor);
    k_fill<<<E_EDGES / 256, 256, 0, stream>>>(srcI, dstI, cursor, csr_src);

    k_conv0<<<N_NODES, 128, 0, stream>>>(x, row_ptr, csr_src, Ws0, Wn0, b0, bufA);
    k_agg<<<N_NODES, 128, 0, stream>>>(bufA, row_ptr, csr_src, bufB);
    k_conv1mm<<<(N_NODES + 63) / 64, 256, 0, stream>>>(bufA, bufB, Ws1, Wn1, b1);

    k_prepf<<<128, 256, 0, stream>>>(Wih0, Whh0, Wih1, Whh1, WTf);
    k_bsum<<<4, 256, 0, stream>>>(bih0, bhh0, bih1, bhh1, bsB);

    // layer 0: fp32 conv output -> H0 (frag-order bf16)
    k_lstm_layer<<<63, 512, 0, stream>>>(bufB, nullptr, WTf, bsB, H0f, nullptr, 0);
    // layer 1: H0 -> pooled (fused mean-pool accumulation)
    k_lstm_layer<<<63, 512, 0, stream>>>(nullptr, H0f, WTf + 131072, bsB + 512, nullptr, pooled, 1);

    k_head<<<1, 128, 0, stream>>>(pooled, Wout, bout, out);
}

// Round 5
// 975.863 us; speedup vs baseline: 2.2034x; 1.0320x over previous
//
#include <hip/hip_runtime.h>

#define N_NODES 100000
#define NPG     1000
#define B_GR    100
#define HDIM    128
#define E_EDGES 1600000

typedef __attribute__((ext_vector_type(8))) short bf16x8;
typedef __attribute__((ext_vector_type(4))) float f32x4;
typedef unsigned long long u64;
typedef unsigned short u16;

// ---------- helpers ----------
__device__ __forceinline__ float sigf(float x) { return 1.f / (1.f + __expf(-x)); }
__device__ __forceinline__ float tanh_fast(float x) { return 1.f - 2.f / (__expf(2.f * x) + 1.f); }
__device__ __forceinline__ u16 f2bf(float f) {
    unsigned u = __float_as_uint(f);
    unsigned r = (u + 0x7fffu + ((u >> 16) & 1u)) >> 16;
    return (u16)r;
}
__device__ __forceinline__ bf16x8 pack8(f32x4 a, f32x4 b) {
    bf16x8 r;
    r[0] = (short)f2bf(a[0]); r[1] = (short)f2bf(a[1]);
    r[2] = (short)f2bf(a[2]); r[3] = (short)f2bf(a[3]);
    r[4] = (short)f2bf(b[0]); r[5] = (short)f2bf(b[1]);
    r[6] = (short)f2bf(b[2]); r[7] = (short)f2bf(b[3]);
    return r;
}

// ---------- CSR build (R2 verbatim) ----------
__global__ void k_count(const int* __restrict__ dst, int* __restrict__ cnt) {
    int e = blockIdx.x * 256 + threadIdx.x;
    if (e < E_EDGES) atomicAdd(&cnt[dst[e]], 1);
}

__global__ void k_scan1(const int* __restrict__ cnt, int* __restrict__ row_ptr, int* __restrict__ bsum) {
    __shared__ int sd[256];
    int tid = threadIdx.x;
    int base = blockIdx.x * 1024 + tid * 4;
    int v[4];
#pragma unroll
    for (int j = 0; j < 4; ++j) {
        int i = base + j;
        v[j] = (i < N_NODES) ? cnt[i] : 0;
    }
    int s = v[0] + v[1] + v[2] + v[3];
    sd[tid] = s;
    __syncthreads();
    for (int off = 1; off < 256; off <<= 1) {
        int t = (tid >= off) ? sd[tid - off] : 0;
        __syncthreads();
        sd[tid] += t;
        __syncthreads();
    }
    int excl = sd[tid] - s;
    int run = excl;
#pragma unroll
    for (int j = 0; j < 4; ++j) {
        int i = base + j;
        run += v[j];
        if (i < N_NODES) row_ptr[1 + i] = run;
    }
    if (tid == 255) bsum[blockIdx.x] = sd[255];
}

__global__ void k_scan2(int* __restrict__ bsum, int nb) {
    if (threadIdx.x == 0 && blockIdx.x == 0) {
        int carry = 0;
        for (int b = 0; b < nb; ++b) {
            int t = bsum[b];
            bsum[b] = carry;
            carry += t;
        }
    }
}

__global__ void k_scan3(int* __restrict__ row_ptr, const int* __restrict__ bsum, int* __restrict__ cursor) {
    int i = blockIdx.x * 256 + threadIdx.x;
    if (i >= N_NODES) return;
    int incl = row_ptr[1 + i] + bsum[i >> 10];
    row_ptr[1 + i] = incl;
    if (i == 0) { row_ptr[0] = 0; cursor[0] = 0; }
    if (i + 1 < N_NODES) cursor[i + 1] = incl;
}

__global__ void k_fill(const int* __restrict__ src, const int* __restrict__ dst,
                       int* __restrict__ cursor, int* __restrict__ csr_src) {
    int e = blockIdx.x * 256 + threadIdx.x;
    if (e >= E_EDGES) return;
    int d = dst[e];
    int pos = atomicAdd(&cursor[d], 1);
    csr_src[pos] = src[e];
}

// ---------- conv layer 0 (R2 verbatim, fp32) ----------
__global__ void k_conv0(const float* __restrict__ x, const int* __restrict__ rp, const int* __restrict__ csr,
                        const float* __restrict__ Ws, const float* __restrict__ Wn, const float* __restrict__ b,
                        float* __restrict__ out) {
    int n = blockIdx.x;
    int tid = threadIdx.x;
    __shared__ float sagg[3];
    if (tid < 3) sagg[tid] = 0.f;
    __syncthreads();
    int s0 = rp[n], s1 = rp[n + 1];
    int deg = s1 - s0;
    for (int j = tid; j < deg; j += 128) {
        int s = csr[s0 + j];
        atomicAdd(&sagg[0], x[s * 3 + 0]);
        atomicAdd(&sagg[1], x[s * 3 + 1]);
        atomicAdd(&sagg[2], x[s * 3 + 2]);
    }
    __syncthreads();
    float inv = 1.f / fmaxf((float)deg, 1.f);
    float a0 = sagg[0] * inv, a1 = sagg[1] * inv, a2 = sagg[2] * inv;
    float x0 = x[n * 3 + 0], x1 = x[n * 3 + 1], x2 = x[n * 3 + 2];
    float acc = b[tid]
        + x0 * Ws[0 * 128 + tid] + x1 * Ws[1 * 128 + tid] + x2 * Ws[2 * 128 + tid]
        + a0 * Wn[0 * 128 + tid] + a1 * Wn[1 * 128 + tid] + a2 * Wn[2 * 128 + tid];
    out[n * 128 + tid] = fmaxf(acc, 0.f);
}

// ---------- conv layer 1 neighbor aggregation (R2 verbatim, fp32) ----------
__global__ void k_agg(const float* __restrict__ hin, const int* __restrict__ rp, const int* __restrict__ csr,
                      float* __restrict__ out) {
    int n = blockIdx.x;
    int tid = threadIdx.x;
    __shared__ int sidx[128];
    int s0 = rp[n], s1 = rp[n + 1];
    int deg = s1 - s0;
    float acc = 0.f;
    for (int base = 0; base < deg; base += 128) {
        int m = min(128, deg - base);
        if (tid < m) sidx[tid] = csr[s0 + base + tid];
        __syncthreads();
        for (int j = 0; j < m; ++j) acc += hin[sidx[j] * 128 + tid];
        __syncthreads();
    }
    out[n * 128 + tid] = acc / fmaxf((float)deg, 1.f);
}

// ---------- conv layer 1 transform (R2 verbatim, fp32): B <- relu(A@Wself + B@Wnbr + bias) ----------
__global__ __launch_bounds__(256)
void k_conv1mm(const float* __restrict__ A, float* __restrict__ B,
               const float* __restrict__ Wself, const float* __restrict__ Wnbr,
               const float* __restrict__ bias) {
    __shared__ float As[64 * 64];
    __shared__ float Wls[64 * 128];
    int tid = threadIdx.x;
    int r0 = blockIdx.x * 64;
    int tx = tid & 31, ty = tid >> 5;
    float acc[8][4];
#pragma unroll
    for (int r = 0; r < 8; ++r)
#pragma unroll
        for (int j = 0; j < 4; ++j) acc[r][j] = 0.f;

    for (int chunk = 0; chunk < 4; ++chunk) {
        const float* Asrc = (chunk < 2) ? A : B;
        const float* Wsrc = (chunk < 2) ? Wself : Wnbr;
        int k0 = (chunk & 1) * 64;
#pragma unroll
        for (int i = 0; i < 4; ++i) {
            int e = tid + 256 * i;
            int row = e >> 4, c4 = e & 15;
            int grow = r0 + row;
            float4 v = make_float4(0.f, 0.f, 0.f, 0.f);
            if (grow < N_NODES) v = *(const float4*)&Asrc[grow * 128 + k0 + c4 * 4];
            *(float4*)&As[row * 64 + c4 * 4] = v;
        }
#pragma unroll
        for (int i = 0; i < 8; ++i) {
            int e = tid + 256 * i;
            int row = e >> 5, c4 = e & 31;
            *(float4*)&Wls[row * 128 + c4 * 4] = *(const float4*)&Wsrc[(k0 + row) * 128 + c4 * 4];
        }
        __syncthreads();
#pragma unroll 4
        for (int kk = 0; kk < 64; ++kk) {
            float4 w = *(const float4*)&Wls[kk * 128 + tx * 4];
#pragma unroll
            for (int r = 0; r < 8; ++r) {
                float a = As[(ty + 8 * r) * 64 + kk];
                acc[r][0] += a * w.x; acc[r][1] += a * w.y;
                acc[r][2] += a * w.z; acc[r][3] += a * w.w;
            }
        }
        __syncthreads();
    }
    float4 bb = *(const float4*)&bias[tx * 4];
#pragma unroll
    for (int r = 0; r < 8; ++r) {
        int grow = r0 + ty + 8 * r;
        if (grow < N_NODES) {
            float4 v;
            v.x = fmaxf(acc[r][0] + bb.x, 0.f);
            v.y = fmaxf(acc[r][1] + bb.y, 0.f);
            v.z = fmaxf(acc[r][2] + bb.z, 0.f);
            v.w = fmaxf(acc[r][3] + bb.w, 0.f);
            *(float4*)&B[grow * 128 + tx * 4] = v;
        }
    }
}

// ---------- LSTM weight prep (R2 verbatim) ----------
__global__ void k_prepf(const float* __restrict__ Wih0, const float* __restrict__ Whh0,
                        const float* __restrict__ Wih1, const float* __restrict__ Whh1,
                        u16* __restrict__ WTf) {
    int idx = blockIdx.x * 256 + threadIdx.x;   // 0..32767
    int lane = idx & 63;
    int gt = (idx >> 6) & 3;
    int kt = (idx >> 8) & 7;
    int w  = (idx >> 11) & 7;
    int l  = idx >> 14;
    int d = 16 * w + (lane & 15);
    int k0 = kt * 32 + (lane >> 4) * 8;
    int wrow = gt * 128 + d;
    const float* Wi = l ? Wih1 : Wih0;
    const float* Wh = l ? Whh1 : Whh0;
    const float* srcp = (k0 < 128) ? (Wi + wrow * 128 + k0) : (Wh + wrow * 128 + (k0 - 128));
    u16 o[8];
#pragma unroll
    for (int j = 0; j < 8; ++j) o[j] = f2bf(srcp[j]);
    u64* dst = (u64*)(WTf + (size_t)idx * 8);
    dst[0] = (u64)o[0] | ((u64)o[1] << 16) | ((u64)o[2] << 32) | ((u64)o[3] << 48);
    dst[1] = (u64)o[4] | ((u64)o[5] << 16) | ((u64)o[6] << 32) | ((u64)o[7] << 48);
}

__global__ void k_bsum(const float* __restrict__ bih0, const float* __restrict__ bhh0,
                       const float* __restrict__ bih1, const float* __restrict__ bhh1,
                       float* __restrict__ bs) {
    int i = blockIdx.x * 256 + threadIdx.x; // 0..1023
    int l = i >> 9, c = i & 511;
    bs[i] = l ? (bih1[c] + bhh1[c]) : (bih0[c] + bhh0[c]);
}

// ---------- single-layer persistent LSTM, register weights, 1 barrier/step ----------
// mode 0: reads fp32 X32 (conv out), rounds to bf16 at ingest (== R2 numerics), writes H0f frag tiles
// mode 1: reads H0f frag tiles, accumulates pooled
__global__ __launch_bounds__(512)
void k_lstm_layer(const float* __restrict__ X32, const u16* __restrict__ Xf,
                  const u16* __restrict__ WTl, const float* __restrict__ bsL,
                  u16* __restrict__ H0f, float* __restrict__ pooled, int mode) {
    __shared__ __align__(16) u16 hsh[2][2048];
    int tid = threadIdx.x;
    int l = tid & 63;
    int w = tid >> 6;
    int rb = blockIdx.x;
    int n0 = rb * 16;
    int nreal = min(16, NPG - n0);

    // preload this wave's 32 B-fragments (gate-aligned columns)
    bf16x8 Bw[8][4];
    const bf16x8* Wv = (const bf16x8*)WTl;
#pragma unroll
    for (int kt = 0; kt < 8; ++kt)
#pragma unroll
        for (int gt = 0; gt < 4; ++gt)
            Bw[kt][gt] = Wv[((w * 8 + kt) * 4 + gt) * 64 + l];

    int d = (w << 4) | (l & 15);
    float bi = bsL[d], bf_ = bsL[128 + d], bg = bsL[256 + d], bo = bsL[384 + d];
    float cst0 = 0.f, cst1 = 0.f, cst2 = 0.f, cst3 = 0.f;

    int ktp = d >> 5, oct = (d >> 3) & 3, boff = d & 7;
    int hbase = ktp * 512 + ((l >> 4) * 4 + 16 * oct) * 8 + boff;

    int rowq = min(n0 + (l & 15), NPG - 1);
    int koff = (l >> 4) * 8;
    const float* x32p = X32 ? (X32 + (size_t)rowq * 128 + koff) : nullptr;
    const u16*  xfp  = Xf ? (Xf + (size_t)rb * 2048 + l * 8) : nullptr;

    f32x4 xr[8];
    bf16x8 xf[4];
    if (mode == 0) {
#pragma unroll
        for (int kt = 0; kt < 4; ++kt) {
            xr[2 * kt]     = *(const f32x4*)(x32p + kt * 32);
            xr[2 * kt + 1] = *(const f32x4*)(x32p + kt * 32 + 4);
        }
    } else {
#pragma unroll
        for (int kt = 0; kt < 4; ++kt)
            xf[kt] = *(const bf16x8*)(xfp + kt * 512);
    }

    ((u64*)hsh[0])[tid] = 0ull;
    __syncthreads();
    int cur = 0;

    for (int t = 0; t < 100; ++t) {
        // x operand for this step (regs only)
        bf16x8 xa[4];
        if (mode == 0) {
#pragma unroll
            for (int kt = 0; kt < 4; ++kt) xa[kt] = pack8(xr[2 * kt], xr[2 * kt + 1]);
        } else {
#pragma unroll
            for (int kt = 0; kt < 4; ++kt) xa[kt] = xf[kt];
        }

        // x-part MFMAs (pre-barrier, register-only)
        f32x4 acc[4];
#pragma unroll
        for (int gt = 0; gt < 4; ++gt) acc[gt] = (f32x4){0.f, 0.f, 0.f, 0.f};
#pragma unroll
        for (int kt = 0; kt < 4; ++kt) {
            acc[0] = __builtin_amdgcn_mfma_f32_16x16x32_bf16(xa[kt], Bw[kt][0], acc[0], 0, 0, 0);
            acc[1] = __builtin_amdgcn_mfma_f32_16x16x32_bf16(xa[kt], Bw[kt][1], acc[1], 0, 0, 0);
            acc[2] = __builtin_amdgcn_mfma_f32_16x16x32_bf16(xa[kt], Bw[kt][2], acc[2], 0, 0, 0);
            acc[3] = __builtin_amdgcn_mfma_f32_16x16x32_bf16(xa[kt], Bw[kt][3], acc[3], 0, 0, 0);
        }
        __syncthreads();   // hsh[cur] = h(t-1) complete; prior reads of hsh[cur^1] drained

        // handoff copy of h(t-1) to global (mode 0), overlaps h-MFMAs
        if (mode == 0 && t > 0)
            ((u64*)(H0f + (size_t)((t - 1) * 63 + rb) * 2048))[tid] = ((const u64*)hsh[cur])[tid];

        // prefetch x(t+1): latency hidden under h-MFMAs + gates
        if (t < 99) {
            if (mode == 0) {
                const float* xn = x32p + (size_t)(t + 1) * NPG * 128;
#pragma unroll
                for (int kt = 0; kt < 4; ++kt) {
                    xr[2 * kt]     = *(const f32x4*)(xn + kt * 32);
                    xr[2 * kt + 1] = *(const f32x4*)(xn + kt * 32 + 4);
                }
            } else {
                const u16* xn = xfp + (size_t)(t + 1) * 63 * 2048;
#pragma unroll
                for (int kt = 0; kt < 4; ++kt)
                    xf[kt] = *(const bf16x8*)(xn + kt * 512);
            }
        }

        // h-part MFMAs (LDS)
#pragma unroll
        for (int kt = 4; kt < 8; ++kt) {
            bf16x8 af = *(const bf16x8*)(hsh[cur] + (kt & 3) * 512 + l * 8);
            acc[0] = __builtin_amdgcn_mfma_f32_16x16x32_bf16(af, Bw[kt][0], acc[0], 0, 0, 0);
            acc[1] = __builtin_amdgcn_mfma_f32_16x16x32_bf16(af, Bw[kt][1], acc[1], 0, 0, 0);
            acc[2] = __builtin_amdgcn_mfma_f32_16x16x32_bf16(af, Bw[kt][2], acc[2], 0, 0, 0);
            acc[3] = __builtin_amdgcn_mfma_f32_16x16x32_bf16(af, Bw[kt][3], acc[3], 0, 0, 0);
        }

        // gates in-register; h(t) -> hsh[cur^1]
        float hsum = 0.f;
#pragma unroll
        for (int reg = 0; reg < 4; ++reg) {
            float gi = acc[0][reg] + bi;
            float gf = acc[1][reg] + bf_;
            float gg = acc[2][reg] + bg;
            float go = acc[3][reg] + bo;
            float cprev = (reg == 0) ? cst0 : (reg == 1) ? cst1 : (reg == 2) ? cst2 : cst3;
            float c = sigf(gf) * cprev + sigf(gi) * tanh_fast(gg);
            if (reg == 0) cst0 = c; else if (reg == 1) cst1 = c; else if (reg == 2) cst2 = c; else cst3 = c;
            float h = sigf(go) * tanh_fast(c);
            hsh[cur ^ 1][hbase + reg * 8] = f2bf(h);
            if (mode == 1) {
                int row = (l >> 4) * 4 + reg;
                if (row < nreal) hsum += h;
            }
        }
        if (mode == 1) {
            hsum += __shfl_xor(hsum, 16);
            hsum += __shfl_xor(hsum, 32);
            if ((l >> 4) == 0) atomicAdd(&pooled[t * 128 + d], hsum);
        }
        cur ^= 1;
    }
    if (mode == 0) {
        __syncthreads();
        ((u64*)(H0f + (size_t)(99 * 63 + rb) * 2048))[tid] = ((const u64*)hsh[cur])[tid];
    }
}

// ---------- head (R2 verbatim) ----------
__global__ void k_head(const float* __restrict__ pooled, const float* __restrict__ Wout,
                       const float* __restrict__ bout, float* __restrict__ out) {
    int gi = threadIdx.x;
    if (gi >= B_GR) return;
    float l0 = bout[0], l1 = bout[1];
    for (int d = 0; d < 128; ++d) {
        float p = pooled[gi * 128 + d] / 1000.0f;
        l0 += p * Wout[d * 2 + 0];
        l1 += p * Wout[d * 2 + 1];
    }
    float m = fmaxf(l0, l1);
    float lse = m + logf(__expf(l0 - m) + __expf(l1 - m));
    out[gi * 2 + 0] = l0 - lse;
    out[gi * 2 + 1] = l1 - lse;
}

// ---------- launch ----------
extern "C" void kernel_launch(void* const* d_in, const int* in_sizes, int n_in,
                              void* d_out, int out_size, void* d_ws, size_t ws_size,
                              hipStream_t stream) {
    const float* x    = (const float*)d_in[0];
    const int*   ei   = (const int*)d_in[1];
    const int*   srcI = ei;
    const int*   dstI = ei + E_EDGES;
    const float* Ws0  = (const float*)d_in[3];
    const float* Wn0  = (const float*)d_in[4];
    const float* b0   = (const float*)d_in[5];
    const float* Ws1  = (const float*)d_in[6];
    const float* Wn1  = (const float*)d_in[7];
    const float* b1   = (const float*)d_in[8];
    const float* Wih0 = (const float*)d_in[9];
    const float* Whh0 = (const float*)d_in[10];
    const float* bih0 = (const float*)d_in[11];
    const float* bhh0 = (const float*)d_in[12];
    const float* Wih1 = (const float*)d_in[13];
    const float* Whh1 = (const float*)d_in[14];
    const float* bih1 = (const float*)d_in[15];
    const float* bhh1 = (const float*)d_in[16];
    const float* Wout = (const float*)d_in[17];
    const float* bout = (const float*)d_in[18];
    float* out = (float*)d_out;

    char* ws = (char*)d_ws;
    int*   row_ptr = (int*)(ws + 0);            // (N+1) ints, padded region 400128 B
    int*   cursor  = (int*)(ws + 400128);       // N ints           -> 800128
    int*   csr_src = (int*)(ws + 800128);       // E ints           -> 7200128
    int*   bsum    = (int*)(ws + 7200128);      // 128 ints         -> 7200640
    float* bufA    = (float*)(ws + 7200640);    // N*128 f32        -> 58400640  (reused as H0f)
    float* bufB    = (float*)(ws + 58400640);   // N*128 f32        -> 109600640
    u16*   WTf     = (u16*)(ws + 109600640);    // 2*256*512 bf16   -> 110124928
    float* bsB     = (float*)(ws + 110649216);  // 1024 f32         -> 110653312
    float* pooled  = (float*)(ws + 110653312);  // 100*128 f32      -> 110704512

    u16* H0f = (u16*)bufA;  // 100*63*2048 bf16 = 25.8MB, fits in bufA (free after conv1mm)

    hipMemsetAsync(cursor, 0, N_NODES * sizeof(int), stream);
    hipMemsetAsync(pooled, 0, B_GR * 128 * sizeof(float), stream);

    k_count<<<E_EDGES / 256, 256, 0, stream>>>(dstI, cursor);
    k_scan1<<<98, 256, 0, stream>>>(cursor, row_ptr, bsum);
    k_scan2<<<1, 64, 0, stream>>>(bsum, 98);
    k_scan3<<<(N_NODES + 255) / 256, 256, 0, stream>>>(row_ptr, bsum, cursor);
    k_fill<<<E_EDGES / 256, 256, 0, stream>>>(srcI, dstI, cursor, csr_src);

    k_conv0<<<N_NODES, 128, 0, stream>>>(x, row_ptr, csr_src, Ws0, Wn0, b0, bufA);
    k_agg<<<N_NODES, 128, 0, stream>>>(bufA, row_ptr, csr_src, bufB);
    k_conv1mm<<<(N_NODES + 63) / 64, 256, 0, stream>>>(bufA, bufB, Ws1, Wn1, b1);

    k_prepf<<<128, 256, 0, stream>>>(Wih0, Whh0, Wih1, Whh1, WTf);
    k_bsum<<<4, 256, 0, stream>>>(bih0, bhh0, bih1, bhh1, bsB);

    // layer 0: fp32 conv output -> H0f (frag-order bf16); layer 1: H0f -> pooled
    k_lstm_layer<<<63, 512, 0, stream>>>(bufB, nullptr, WTf, bsB, H0f, nullptr, 0);
    k_lstm_layer<<<63, 512, 0, stream>>>(nullptr, H0f, WTf + 131072, bsB + 512, nullptr, pooled, 1);

    k_head<<<1, 128, 0, stream>>>(pooled, Wout, bout, out);
}

// Round 6
// 885.764 us; speedup vs baseline: 2.4275x; 1.1017x over previous
//
#include <hip/hip_runtime.h>

#define N_NODES 100000
#define NPG     1000
#define B_GR    100
#define HDIM    128
#define E_EDGES 1600000

typedef __attribute__((ext_vector_type(8))) short bf16x8;
typedef __attribute__((ext_vector_type(4))) float f32x4;
typedef unsigned long long u64;
typedef unsigned short u16;

// ---------- helpers ----------
__device__ __forceinline__ float sigf(float x) { return 1.f / (1.f + __expf(-x)); }
__device__ __forceinline__ float tanh_fast(float x) { return 1.f - 2.f / (__expf(2.f * x) + 1.f); }
__device__ __forceinline__ u16 f2bf(float f) {
    unsigned u = __float_as_uint(f);
    unsigned r = (u + 0x7fffu + ((u >> 16) & 1u)) >> 16;
    return (u16)r;
}
__device__ __forceinline__ f32x4 MF(bf16x8 a, bf16x8 b, f32x4 c) {
    return __builtin_amdgcn_mfma_f32_16x16x32_bf16(a, b, c, 0, 0, 0);
}
// barrier that drains LDS ops only (no vmcnt(0) drain of global prefetch/stores)
#define BAR() asm volatile("s_waitcnt lgkmcnt(0)\n\ts_barrier" ::: "memory")

// ---------- CSR build (R5 verbatim) ----------
__global__ void k_count(const int* __restrict__ dst, int* __restrict__ cnt) {
    int e = blockIdx.x * 256 + threadIdx.x;
    if (e < E_EDGES) atomicAdd(&cnt[dst[e]], 1);
}

__global__ void k_scan1(const int* __restrict__ cnt, int* __restrict__ row_ptr, int* __restrict__ bsum) {
    __shared__ int sd[256];
    int tid = threadIdx.x;
    int base = blockIdx.x * 1024 + tid * 4;
    int v[4];
#pragma unroll
    for (int j = 0; j < 4; ++j) {
        int i = base + j;
        v[j] = (i < N_NODES) ? cnt[i] : 0;
    }
    int s = v[0] + v[1] + v[2] + v[3];
    sd[tid] = s;
    __syncthreads();
    for (int off = 1; off < 256; off <<= 1) {
        int t = (tid >= off) ? sd[tid - off] : 0;
        __syncthreads();
        sd[tid] += t;
        __syncthreads();
    }
    int excl = sd[tid] - s;
    int run = excl;
#pragma unroll
    for (int j = 0; j < 4; ++j) {
        int i = base + j;
        run += v[j];
        if (i < N_NODES) row_ptr[1 + i] = run;
    }
    if (tid == 255) bsum[blockIdx.x] = sd[255];
}

__global__ void k_scan2(int* __restrict__ bsum, int nb) {
    if (threadIdx.x == 0 && blockIdx.x == 0) {
        int carry = 0;
        for (int b = 0; b < nb; ++b) {
            int t = bsum[b];
            bsum[b] = carry;
            carry += t;
        }
    }
}

__global__ void k_scan3(int* __restrict__ row_ptr, const int* __restrict__ bsum, int* __restrict__ cursor) {
    int i = blockIdx.x * 256 + threadIdx.x;
    if (i >= N_NODES) return;
    int incl = row_ptr[1 + i] + bsum[i >> 10];
    row_ptr[1 + i] = incl;
    if (i == 0) { row_ptr[0] = 0; cursor[0] = 0; }
    if (i + 1 < N_NODES) cursor[i + 1] = incl;
}

__global__ void k_fill(const int* __restrict__ src, const int* __restrict__ dst,
                       int* __restrict__ cursor, int* __restrict__ csr_src) {
    int e = blockIdx.x * 256 + threadIdx.x;
    if (e >= E_EDGES) return;
    int d = dst[e];
    int pos = atomicAdd(&cursor[d], 1);
    csr_src[pos] = src[e];
}

// ---------- conv layer 0 (R5 verbatim, fp32) ----------
__global__ void k_conv0(const float* __restrict__ x, const int* __restrict__ rp, const int* __restrict__ csr,
                        const float* __restrict__ Ws, const float* __restrict__ Wn, const float* __restrict__ b,
                        float* __restrict__ out) {
    int n = blockIdx.x;
    int tid = threadIdx.x;
    __shared__ float sagg[3];
    if (tid < 3) sagg[tid] = 0.f;
    __syncthreads();
    int s0 = rp[n], s1 = rp[n + 1];
    int deg = s1 - s0;
    for (int j = tid; j < deg; j += 128) {
        int s = csr[s0 + j];
        atomicAdd(&sagg[0], x[s * 3 + 0]);
        atomicAdd(&sagg[1], x[s * 3 + 1]);
        atomicAdd(&sagg[2], x[s * 3 + 2]);
    }
    __syncthreads();
    float inv = 1.f / fmaxf((float)deg, 1.f);
    float a0 = sagg[0] * inv, a1 = sagg[1] * inv, a2 = sagg[2] * inv;
    float x0 = x[n * 3 + 0], x1 = x[n * 3 + 1], x2 = x[n * 3 + 2];
    float acc = b[tid]
        + x0 * Ws[0 * 128 + tid] + x1 * Ws[1 * 128 + tid] + x2 * Ws[2 * 128 + tid]
        + a0 * Wn[0 * 128 + tid] + a1 * Wn[1 * 128 + tid] + a2 * Wn[2 * 128 + tid];
    out[n * 128 + tid] = fmaxf(acc, 0.f);
}

// ---------- agg2: wave per node, reg-held indices, 4-wide batched loads ----------
__global__ __launch_bounds__(256)
void k_agg2(const float* __restrict__ hin, const int* __restrict__ rp, const int* __restrict__ csr,
            float* __restrict__ out) {
    int wid = threadIdx.x >> 6;
    int l = threadIdx.x & 63;
    int n = blockIdx.x * 4 + wid;
    if (n >= N_NODES) return;
    int s0 = rp[n], deg = rp[n + 1] - s0;
    float ax = 0.f, ay = 0.f;
    const float2* base = (const float2*)hin;
    for (int c0 = 0; c0 < deg; c0 += 64) {
        int m = min(64, deg - c0);
        int myidx = csr[s0 + c0 + ((l < m) ? l : 0)];
        int j = 0;
        for (; j + 4 <= m; j += 4) {
            int i0 = __shfl(myidx, j);
            int i1 = __shfl(myidx, j + 1);
            int i2 = __shfl(myidx, j + 2);
            int i3 = __shfl(myidx, j + 3);
            float2 v0 = base[(size_t)i0 * 64 + l];
            float2 v1 = base[(size_t)i1 * 64 + l];
            float2 v2 = base[(size_t)i2 * 64 + l];
            float2 v3 = base[(size_t)i3 * 64 + l];
            ax += v0.x; ay += v0.y;
            ax += v1.x; ay += v1.y;
            ax += v2.x; ay += v2.y;
            ax += v3.x; ay += v3.y;
        }
        for (; j < m; ++j) {
            int i0 = __shfl(myidx, j);
            float2 v = base[(size_t)i0 * 64 + l];
            ax += v.x; ay += v.y;
        }
    }
    float dv = fmaxf((float)deg, 1.f);
    float2 o; o.x = ax / dv; o.y = ay / dv;
    *(float2*)&out[(size_t)n * 128 + l * 2] = o;
}

// ---------- conv layer 1 transform (R5 verbatim, fp32) ----------
__global__ __launch_bounds__(256)
void k_conv1mm(const float* __restrict__ A, float* __restrict__ B,
               const float* __restrict__ Wself, const float* __restrict__ Wnbr,
               const float* __restrict__ bias) {
    __shared__ float As[64 * 64];
    __shared__ float Wls[64 * 128];
    int tid = threadIdx.x;
    int r0 = blockIdx.x * 64;
    int tx = tid & 31, ty = tid >> 5;
    float acc[8][4];
#pragma unroll
    for (int r = 0; r < 8; ++r)
#pragma unroll
        for (int j = 0; j < 4; ++j) acc[r][j] = 0.f;

    for (int chunk = 0; chunk < 4; ++chunk) {
        const float* Asrc = (chunk < 2) ? A : B;
        const float* Wsrc = (chunk < 2) ? Wself : Wnbr;
        int k0 = (chunk & 1) * 64;
#pragma unroll
        for (int i = 0; i < 4; ++i) {
            int e = tid + 256 * i;
            int row = e >> 4, c4 = e & 15;
            int grow = r0 + row;
            float4 v = make_float4(0.f, 0.f, 0.f, 0.f);
            if (grow < N_NODES) v = *(const float4*)&Asrc[grow * 128 + k0 + c4 * 4];
            *(float4*)&As[row * 64 + c4 * 4] = v;
        }
#pragma unroll
        for (int i = 0; i < 8; ++i) {
            int e = tid + 256 * i;
            int row = e >> 5, c4 = e & 31;
            *(float4*)&Wls[row * 128 + c4 * 4] = *(const float4*)&Wsrc[(k0 + row) * 128 + c4 * 4];
        }
        __syncthreads();
#pragma unroll 4
        for (int kk = 0; kk < 64; ++kk) {
            float4 w = *(const float4*)&Wls[kk * 128 + tx * 4];
#pragma unroll
            for (int r = 0; r < 8; ++r) {
                float a = As[(ty + 8 * r) * 64 + kk];
                acc[r][0] += a * w.x; acc[r][1] += a * w.y;
                acc[r][2] += a * w.z; acc[r][3] += a * w.w;
            }
        }
        __syncthreads();
    }
    float4 bb = *(const float4*)&bias[tx * 4];
#pragma unroll
    for (int r = 0; r < 8; ++r) {
        int grow = r0 + ty + 8 * r;
        if (grow < N_NODES) {
            float4 v;
            v.x = fmaxf(acc[r][0] + bb.x, 0.f);
            v.y = fmaxf(acc[r][1] + bb.y, 0.f);
            v.z = fmaxf(acc[r][2] + bb.z, 0.f);
            v.w = fmaxf(acc[r][3] + bb.w, 0.f);
            *(float4*)&B[grow * 128 + tx * 4] = v;
        }
    }
}

// ---------- convert conv output fp32 -> bf16 frag-order tiles (same f2bf as R5 pack8) ----------
// virtual rows 1008/graph: rows 1000..1007 duplicate row 999 (matches R5's rowq clamp)
__global__ void k_tobf16(const float* __restrict__ C, u16* __restrict__ Xf) {
    int g = blockIdx.x * 256 + threadIdx.x;   // 0 .. 3,225,599
    int vr = g >> 5;                          // virtual row 0..100799
    int c4 = g & 31;
    int t = vr / 1008;
    int rv = vr - t * 1008;
    int r = min(rv, NPG - 1);
    int n = t * NPG + r;
    int col0 = c4 * 4;
    f32x4 v = *(const f32x4*)(C + (size_t)n * 128 + col0);
    u16 h0 = f2bf(v[0]), h1 = f2bf(v[1]), h2 = f2bf(v[2]), h3 = f2bf(v[3]);
    u64 pk = (u64)h0 | ((u64)h1 << 16) | ((u64)h2 << 32) | ((u64)h3 << 48);
    int rb = rv >> 4, rr = rv & 15;
    size_t idx = (size_t)(t * 63 + rb) * 2048
               + (size_t)((col0 >> 5) * 512 + ((col0 >> 3) & 3) * 128 + rr * 8 + (col0 & 7));
    *(u64*)(Xf + idx) = pk;
}

// ---------- LSTM weight prep (R5 verbatim) ----------
__global__ void k_prepf(const float* __restrict__ Wih0, const float* __restrict__ Whh0,
                        const float* __restrict__ Wih1, const float* __restrict__ Whh1,
                        u16* __restrict__ WTf) {
    int idx = blockIdx.x * 256 + threadIdx.x;   // 0..32767
    int lane = idx & 63;
    int gt = (idx >> 6) & 3;
    int kt = (idx >> 8) & 7;
    int w  = (idx >> 11) & 7;
    int l  = idx >> 14;
    int d = 16 * w + (lane & 15);
    int k0 = kt * 32 + (lane >> 4) * 8;
    int wrow = gt * 128 + d;
    const float* Wi = l ? Wih1 : Wih0;
    const float* Wh = l ? Whh1 : Whh0;
    const float* srcp = (k0 < 128) ? (Wi + wrow * 128 + k0) : (Wh + wrow * 128 + (k0 - 128));
    u16 o[8];
#pragma unroll
    for (int j = 0; j < 8; ++j) o[j] = f2bf(srcp[j]);
    u64* dst = (u64*)(WTf + (size_t)idx * 8);
    dst[0] = (u64)o[0] | ((u64)o[1] << 16) | ((u64)o[2] << 32) | ((u64)o[3] << 48);
    dst[1] = (u64)o[4] | ((u64)o[5] << 16) | ((u64)o[6] << 32) | ((u64)o[7] << 48);
}

__global__ void k_bsum(const float* __restrict__ bih0, const float* __restrict__ bhh0,
                       const float* __restrict__ bih1, const float* __restrict__ bhh1,
                       float* __restrict__ bs) {
    int i = blockIdx.x * 256 + threadIdx.x; // 0..1023
    int l = i >> 9, c = i & 511;
    bs[i] = l ? (bih1[c] + bhh1[c]) : (bih0[c] + bhh0[c]);
}

// ---------- LSTM layer: register weights, pipelined x-MFMA, LDS-only barrier ----------
// Input always frag-order bf16 tiles [(t*63+rb)*2048]. mode 0 writes Hout tiles; mode 1 pools.
#define LSTM_STEP(ACC, ACCN, T, CUR)                                                   \
    do {                                                                               \
        BAR();                                                                         \
        _Pragma("unroll")                                                              \
        for (int kt = 0; kt < 4; ++kt) {                                               \
            bf16x8 af = *(const bf16x8*)(hsh[CUR] + kt * 512 + l * 8);                 \
            ACC[0] = MF(af, Bw[4 + kt][0], ACC[0]);                                    \
            ACC[1] = MF(af, Bw[4 + kt][1], ACC[1]);                                    \
            ACC[2] = MF(af, Bw[4 + kt][2], ACC[2]);                                    \
            ACC[3] = MF(af, Bw[4 + kt][3], ACC[3]);                                    \
        }                                                                              \
        if (mode == 0 && (T) > 0)                                                      \
            ((u64*)(Hout + (size_t)(((T) - 1) * 63 + rb) * 2048))[tid] =               \
                ((const u64*)hsh[CUR])[tid];                                           \
        if ((T) < 99) {                                                                \
            _Pragma("unroll")                                                          \
            for (int g = 0; g < 4; ++g) ACCN[g] = (f32x4){0.f, 0.f, 0.f, 0.f};         \
            _Pragma("unroll")                                                          \
            for (int kt = 0; kt < 4; ++kt) {                                           \
                ACCN[0] = MF(xf[kt], Bw[kt][0], ACCN[0]);                              \
                ACCN[1] = MF(xf[kt], Bw[kt][1], ACCN[1]);                              \
                ACCN[2] = MF(xf[kt], Bw[kt][2], ACCN[2]);                              \
                ACCN[3] = MF(xf[kt], Bw[kt][3], ACCN[3]);                              \
            }                                                                          \
        }                                                                              \
        if ((T) < 98) {                                                                \
            const u16* xn = xbase + (size_t)((T) + 2) * TSTR;                          \
            _Pragma("unroll")                                                          \
            for (int kt = 0; kt < 4; ++kt)                                             \
                xf[kt] = *(const bf16x8*)(xn + kt * 512);                              \
        }                                                                              \
        float hsum = 0.f;                                                              \
        _Pragma("unroll")                                                              \
        for (int reg = 0; reg < 4; ++reg) {                                            \
            float gi = ACC[0][reg] + bi;                                               \
            float gf = ACC[1][reg] + bf_;                                              \
            float gg = ACC[2][reg] + bg;                                               \
            float go = ACC[3][reg] + bo;                                               \
            float cprev = (reg == 0) ? cst0 : (reg == 1) ? cst1 : (reg == 2) ? cst2 : cst3; \
            float c = sigf(gf) * cprev + sigf(gi) * tanh_fast(gg);                     \
            if (reg == 0) cst0 = c; else if (reg == 1) cst1 = c;                       \
            else if (reg == 2) cst2 = c; else cst3 = c;                                \
            float h = sigf(go) * tanh_fast(c);                                         \
            hsh[(CUR) ^ 1][hbase + reg * 8] = f2bf(h);                                 \
            if (mode == 1) {                                                           \
                int row = (l >> 4) * 4 + reg;                                          \
                if (row < nreal) hsum += h;                                            \
            }                                                                          \
        }                                                                              \
        if (mode == 1) {                                                               \
            hsum += __shfl_xor(hsum, 16);                                              \
            hsum += __shfl_xor(hsum, 32);                                              \
            if ((l >> 4) == 0) atomicAdd(&pooled[(T) * 128 + d], hsum);                \
        }                                                                              \
    } while (0)

__global__ __launch_bounds__(512)
void k_lstm_layer(const u16* __restrict__ Xf, const u16* __restrict__ WTl,
                  const float* __restrict__ bsL, u16* __restrict__ Hout,
                  float* __restrict__ pooled, int mode) {
    __shared__ __align__(16) u16 hsh[2][2048];
    int tid = threadIdx.x;
    int l = tid & 63;
    int w = tid >> 6;
    int rb = blockIdx.x;
    int n0 = rb * 16;
    int nreal = min(16, NPG - n0);

    bf16x8 Bw[8][4];
    const bf16x8* Wv = (const bf16x8*)WTl;
#pragma unroll
    for (int kt = 0; kt < 8; ++kt)
#pragma unroll
        for (int gt = 0; gt < 4; ++gt)
            Bw[kt][gt] = Wv[((w * 8 + kt) * 4 + gt) * 64 + l];

    int d = (w << 4) | (l & 15);
    float bi = bsL[d], bf_ = bsL[128 + d], bg = bsL[256 + d], bo = bsL[384 + d];
    float cst0 = 0.f, cst1 = 0.f, cst2 = 0.f, cst3 = 0.f;

    int ktp = d >> 5, oct = (d >> 3) & 3, boff = d & 7;
    int hbase = ktp * 512 + ((l >> 4) * 4 + 16 * oct) * 8 + boff;

    const u16* xbase = Xf + (size_t)rb * 2048 + l * 8;
    const size_t TSTR = (size_t)63 * 2048;

    // prologue: tile 0 -> accA x-part; prefetch tile 1
    bf16x8 xf[4];
#pragma unroll
    for (int kt = 0; kt < 4; ++kt) xf[kt] = *(const bf16x8*)(xbase + kt * 512);

    f32x4 accA[4], accB[4];
#pragma unroll
    for (int g = 0; g < 4; ++g) accA[g] = (f32x4){0.f, 0.f, 0.f, 0.f};
#pragma unroll
    for (int kt = 0; kt < 4; ++kt) {
        accA[0] = MF(xf[kt], Bw[kt][0], accA[0]);
        accA[1] = MF(xf[kt], Bw[kt][1], accA[1]);
        accA[2] = MF(xf[kt], Bw[kt][2], accA[2]);
        accA[3] = MF(xf[kt], Bw[kt][3], accA[3]);
    }
#pragma unroll
    for (int kt = 0; kt < 4; ++kt) xf[kt] = *(const bf16x8*)(xbase + TSTR + kt * 512);

    ((u64*)hsh[0])[tid] = 0ull;

    for (int t2 = 0; t2 < 50; ++t2) {
        int t0 = 2 * t2;
        LSTM_STEP(accA, accB, t0, 0);
        LSTM_STEP(accB, accA, t0 + 1, 1);
    }
    BAR();
    if (mode == 0)
        ((u64*)(Hout + (size_t)(99 * 63 + rb) * 2048))[tid] = ((const u64*)hsh[0])[tid];
}

// ---------- head (R5 verbatim) ----------
__global__ void k_head(const float* __restrict__ pooled, const float* __restrict__ Wout,
                       const float* __restrict__ bout, float* __restrict__ out) {
    int gi = threadIdx.x;
    if (gi >= B_GR) return;
    float l0 = bout[0], l1 = bout[1];
    for (int d = 0; d < 128; ++d) {
        float p = pooled[gi * 128 + d] / 1000.0f;
        l0 += p * Wout[d * 2 + 0];
        l1 += p * Wout[d * 2 + 1];
    }
    float m = fmaxf(l0, l1);
    float lse = m + logf(__expf(l0 - m) + __expf(l1 - m));
    out[gi * 2 + 0] = l0 - lse;
    out[gi * 2 + 1] = l1 - lse;
}

// ---------- launch ----------
extern "C" void kernel_launch(void* const* d_in, const int* in_sizes, int n_in,
                              void* d_out, int out_size, void* d_ws, size_t ws_size,
                              hipStream_t stream) {
    const float* x    = (const float*)d_in[0];
    const int*   ei   = (const int*)d_in[1];
    const int*   srcI = ei;
    const int*   dstI = ei + E_EDGES;
    const float* Ws0  = (const float*)d_in[3];
    const float* Wn0  = (const float*)d_in[4];
    const float* b0   = (const float*)d_in[5];
    const float* Ws1  = (const float*)d_in[6];
    const float* Wn1  = (const float*)d_in[7];
    const float* b1   = (const float*)d_in[8];
    const float* Wih0 = (const float*)d_in[9];
    const float* Whh0 = (const float*)d_in[10];
    const float* bih0 = (const float*)d_in[11];
    const float* bhh0 = (const float*)d_in[12];
    const float* Wih1 = (const float*)d_in[13];
    const float* Whh1 = (const float*)d_in[14];
    const float* bih1 = (const float*)d_in[15];
    const float* bhh1 = (const float*)d_in[16];
    const float* Wout = (const float*)d_in[17];
    const float* bout = (const float*)d_in[18];
    float* out = (float*)d_out;

    char* ws = (char*)d_ws;
    int*   row_ptr = (int*)(ws + 0);            // (N+1) ints -> pad 400128
    int*   cursor  = (int*)(ws + 400128);       // N ints     -> 800128
    int*   csr_src = (int*)(ws + 800128);       // E ints     -> 7200128
    int*   bsum    = (int*)(ws + 7200128);      // 512B       -> 7200640
    float* bufA    = (float*)(ws + 7200640);    // N*128 f32  -> 58400640 (reused: Xf + H0f)
    float* bufB    = (float*)(ws + 58400640);   // N*128 f32  -> 109600640 (conv1 out, fp32)
    u16*   WTf     = (u16*)(ws + 109600640);    // 2*256*512 bf16 -> 110124928
    float* bsB     = (float*)(ws + 110649216);  // 1024 f32   -> 110653312
    float* pooled  = (float*)(ws + 110653312);  // 100*128 f32-> 110704512

    // bufA region reuse after conv1mm: Xf tiles (25.8MB) then H0f tiles (25.8MB,
    // tail overlaps dead bufB head -- bufB fully consumed by k_tobf16 first)
    u16* Xf  = (u16*)(ws + 7200640);
    u16* H0f = (u16*)(ws + 33005440);

    hipMemsetAsync(cursor, 0, N_NODES * sizeof(int), stream);
    hipMemsetAsync(pooled, 0, B_GR * 128 * sizeof(float), stream);

    k_count<<<E_EDGES / 256, 256, 0, stream>>>(dstI, cursor);
    k_scan1<<<98, 256, 0, stream>>>(cursor, row_ptr, bsum);
    k_scan2<<<1, 64, 0, stream>>>(bsum, 98);
    k_scan3<<<(N_NODES + 255) / 256, 256, 0, stream>>>(row_ptr, bsum, cursor);
    k_fill<<<E_EDGES / 256, 256, 0, stream>>>(srcI, dstI, cursor, csr_src);

    k_conv0<<<N_NODES, 128, 0, stream>>>(x, row_ptr, csr_src, Ws0, Wn0, b0, bufA);
    k_agg2<<<N_NODES / 4, 256, 0, stream>>>(bufA, row_ptr, csr_src, bufB);
    k_conv1mm<<<(N_NODES + 63) / 64, 256, 0, stream>>>(bufA, bufB, Ws1, Wn1, b1);
    k_tobf16<<<12600, 256, 0, stream>>>(bufB, Xf);

    k_prepf<<<128, 256, 0, stream>>>(Wih0, Whh0, Wih1, Whh1, WTf);
    k_bsum<<<4, 256, 0, stream>>>(bih0, bhh0, bih1, bhh1, bsB);

    k_lstm_layer<<<63, 512, 0, stream>>>(Xf, WTf, bsB, H0f, nullptr, 0);
    k_lstm_layer<<<63, 512, 0, stream>>>(H0f, WTf + 131072, bsB + 512, nullptr, pooled, 1);

    k_head<<<1, 128, 0, stream>>>(pooled, Wout, bout, out);
}

// Round 7
// 838.298 us; speedup vs baseline: 2.5650x; 1.0566x over previous
//
#include <hip/hip_runtime.h>

#define N_NODES 100000
#define NPG     1000
#define B_GR    100
#define HDIM    128
#define E_EDGES 1600000

typedef __attribute__((ext_vector_type(8))) short bf16x8;
typedef __attribute__((ext_vector_type(4))) float f32x4;
typedef unsigned long long u64;
typedef unsigned short u16;

// ---------- helpers ----------
__device__ __forceinline__ float sigf(float x) { return 1.f / (1.f + __expf(-x)); }
__device__ __forceinline__ float tanh_fast(float x) { return 1.f - 2.f / (__expf(2.f * x) + 1.f); }
__device__ __forceinline__ u16 f2bf(float f) {
    unsigned u = __float_as_uint(f);
    unsigned r = (u + 0x7fffu + ((u >> 16) & 1u)) >> 16;
    return (u16)r;
}
__device__ __forceinline__ float bf2f(u16 h) { return __uint_as_float(((unsigned)h) << 16); }
__device__ __forceinline__ f32x4 MF(bf16x8 a, bf16x8 b, f32x4 c) {
    return __builtin_amdgcn_mfma_f32_16x16x32_bf16(a, b, c, 0, 0, 0);
}
// barrier that drains LDS ops only (no vmcnt(0) drain of global prefetch/stores)
#define BAR() asm volatile("s_waitcnt lgkmcnt(0)\n\ts_barrier" ::: "memory")

// ---------- CSR build ----------
__global__ void k_count(const int* __restrict__ dst, int* __restrict__ cnt) {
    int e = blockIdx.x * 256 + threadIdx.x;
    if (e < E_EDGES) atomicAdd(&cnt[dst[e]], 1);
}

__global__ void k_scan1(const int* __restrict__ cnt, int* __restrict__ row_ptr, int* __restrict__ bsum) {
    __shared__ int sd[256];
    int tid = threadIdx.x;
    int base = blockIdx.x * 1024 + tid * 4;
    int v[4];
#pragma unroll
    for (int j = 0; j < 4; ++j) {
        int i = base + j;
        v[j] = (i < N_NODES) ? cnt[i] : 0;
    }
    int s = v[0] + v[1] + v[2] + v[3];
    sd[tid] = s;
    __syncthreads();
    for (int off = 1; off < 256; off <<= 1) {
        int t = (tid >= off) ? sd[tid - off] : 0;
        __syncthreads();
        sd[tid] += t;
        __syncthreads();
    }
    int excl = sd[tid] - s;
    int run = excl;
#pragma unroll
    for (int j = 0; j < 4; ++j) {
        int i = base + j;
        run += v[j];
        if (i < N_NODES) row_ptr[1 + i] = run;
    }
    if (tid == 255) bsum[blockIdx.x] = sd[255];
}

__global__ void k_scan2(int* __restrict__ bsum, int nb) {
    if (threadIdx.x == 0 && blockIdx.x == 0) {
        int carry = 0;
        for (int b = 0; b < nb; ++b) {
            int t = bsum[b];
            bsum[b] = carry;
            carry += t;
        }
    }
}

__global__ void k_scan3(int* __restrict__ row_ptr, const int* __restrict__ bsum, int* __restrict__ cursor) {
    int i = blockIdx.x * 256 + threadIdx.x;
    if (i >= N_NODES) return;
    int incl = row_ptr[1 + i] + bsum[i >> 10];
    row_ptr[1 + i] = incl;
    if (i == 0) { row_ptr[0] = 0; cursor[0] = 0; }
    if (i + 1 < N_NODES) cursor[i + 1] = incl;
}

__global__ void k_fill(const int* __restrict__ src, const int* __restrict__ dst,
                       int* __restrict__ cursor, int* __restrict__ csr_src) {
    int e = blockIdx.x * 256 + threadIdx.x;
    if (e >= E_EDGES) return;
    int d = dst[e];
    int pos = atomicAdd(&cursor[d], 1);
    csr_src[pos] = src[e];
}

// ---------- conv layer 0: same structure as R5, output bf16 ----------
__global__ void k_conv0(const float* __restrict__ x, const int* __restrict__ rp, const int* __restrict__ csr,
                        const float* __restrict__ Ws, const float* __restrict__ Wn, const float* __restrict__ b,
                        u16* __restrict__ Hbf) {
    int n = blockIdx.x;
    int tid = threadIdx.x;
    __shared__ float sagg[3];
    if (tid < 3) sagg[tid] = 0.f;
    __syncthreads();
    int s0 = rp[n], s1 = rp[n + 1];
    int deg = s1 - s0;
    for (int j = tid; j < deg; j += 128) {
        int s = csr[s0 + j];
        atomicAdd(&sagg[0], x[s * 3 + 0]);
        atomicAdd(&sagg[1], x[s * 3 + 1]);
        atomicAdd(&sagg[2], x[s * 3 + 2]);
    }
    __syncthreads();
    float inv = 1.f / fmaxf((float)deg, 1.f);
    float a0 = sagg[0] * inv, a1 = sagg[1] * inv, a2 = sagg[2] * inv;
    float x0 = x[n * 3 + 0], x1 = x[n * 3 + 1], x2 = x[n * 3 + 2];
    float acc = b[tid]
        + x0 * Ws[0 * 128 + tid] + x1 * Ws[1 * 128 + tid] + x2 * Ws[2 * 128 + tid]
        + a0 * Wn[0 * 128 + tid] + a1 * Wn[1 * 128 + tid] + a2 * Wn[2 * 128 + tid];
    Hbf[(size_t)n * 128 + tid] = f2bf(fmaxf(acc, 0.f));
}

// ---------- agg2: wave per node, bf16 gather (u32 = 2 cols/lane), fp32 accumulate ----------
__global__ __launch_bounds__(256)
void k_agg2(const u16* __restrict__ hin, const int* __restrict__ rp, const int* __restrict__ csr,
            float* __restrict__ out) {
    int wid = threadIdx.x >> 6;
    int l = threadIdx.x & 63;
    int n = blockIdx.x * 4 + wid;
    if (n >= N_NODES) return;
    int s0 = rp[n], deg = rp[n + 1] - s0;
    float ax = 0.f, ay = 0.f;
    const unsigned* base = (const unsigned*)hin;   // 2 bf16 per u32; row = 64 u32
    for (int c0 = 0; c0 < deg; c0 += 64) {
        int m = min(64, deg - c0);
        int myidx = csr[s0 + c0 + ((l < m) ? l : 0)];
        int j = 0;
        for (; j + 4 <= m; j += 4) {
            int i0 = __shfl(myidx, j);
            int i1 = __shfl(myidx, j + 1);
            int i2 = __shfl(myidx, j + 2);
            int i3 = __shfl(myidx, j + 3);
            unsigned v0 = base[(size_t)i0 * 64 + l];
            unsigned v1 = base[(size_t)i1 * 64 + l];
            unsigned v2 = base[(size_t)i2 * 64 + l];
            unsigned v3 = base[(size_t)i3 * 64 + l];
            ax += bf2f((u16)v0); ay += bf2f((u16)(v0 >> 16));
            ax += bf2f((u16)v1); ay += bf2f((u16)(v1 >> 16));
            ax += bf2f((u16)v2); ay += bf2f((u16)(v2 >> 16));
            ax += bf2f((u16)v3); ay += bf2f((u16)(v3 >> 16));
        }
        for (; j < m; ++j) {
            int i0 = __shfl(myidx, j);
            unsigned v = base[(size_t)i0 * 64 + l];
            ax += bf2f((u16)v); ay += bf2f((u16)(v >> 16));
        }
    }
    float dv = fmaxf((float)deg, 1.f);
    float2 o; o.x = ax / dv; o.y = ay / dv;
    *(float2*)&out[(size_t)n * 128 + l * 2] = o;
}

// ---------- conv layer 1 transform: B <- relu(A@Wself + B@Wnbr + bias); A from bf16 Hbf ----------
__global__ __launch_bounds__(256)
void k_conv1mm(const u16* __restrict__ Hbf, float* __restrict__ B,
               const float* __restrict__ Wself, const float* __restrict__ Wnbr,
               const float* __restrict__ bias) {
    __shared__ float As[64 * 64];
    __shared__ float Wls[64 * 128];
    int tid = threadIdx.x;
    int r0 = blockIdx.x * 64;
    int tx = tid & 31, ty = tid >> 5;
    float acc[8][4];
#pragma unroll
    for (int r = 0; r < 8; ++r)
#pragma unroll
        for (int j = 0; j < 4; ++j) acc[r][j] = 0.f;

    for (int chunk = 0; chunk < 4; ++chunk) {
        const float* Wsrc = (chunk < 2) ? Wself : Wnbr;
        int k0 = (chunk & 1) * 64;
#pragma unroll
        for (int i = 0; i < 4; ++i) {
            int e = tid + 256 * i;
            int row = e >> 4, c4 = e & 15;
            int grow = r0 + row;
            float4 v = make_float4(0.f, 0.f, 0.f, 0.f);
            if (grow < N_NODES) {
                if (chunk < 2) {
                    u64 p = *(const u64*)&Hbf[(size_t)grow * 128 + k0 + c4 * 4];
                    v.x = bf2f((u16)p);         v.y = bf2f((u16)(p >> 16));
                    v.z = bf2f((u16)(p >> 32)); v.w = bf2f((u16)(p >> 48));
                } else {
                    v = *(const float4*)&B[(size_t)grow * 128 + k0 + c4 * 4];
                }
            }
            *(float4*)&As[row * 64 + c4 * 4] = v;
        }
#pragma unroll
        for (int i = 0; i < 8; ++i) {
            int e = tid + 256 * i;
            int row = e >> 5, c4 = e & 31;
            *(float4*)&Wls[row * 128 + c4 * 4] = *(const float4*)&Wsrc[(k0 + row) * 128 + c4 * 4];
        }
        __syncthreads();
#pragma unroll 4
        for (int kk = 0; kk < 64; ++kk) {
            float4 w = *(const float4*)&Wls[kk * 128 + tx * 4];
#pragma unroll
            for (int r = 0; r < 8; ++r) {
                float a = As[(ty + 8 * r) * 64 + kk];
                acc[r][0] += a * w.x; acc[r][1] += a * w.y;
                acc[r][2] += a * w.z; acc[r][3] += a * w.w;
            }
        }
        __syncthreads();
    }
    float4 bb = *(const float4*)&bias[tx * 4];
#pragma unroll
    for (int r = 0; r < 8; ++r) {
        int grow = r0 + ty + 8 * r;
        if (grow < N_NODES) {
            float4 v;
            v.x = fmaxf(acc[r][0] + bb.x, 0.f);
            v.y = fmaxf(acc[r][1] + bb.y, 0.f);
            v.z = fmaxf(acc[r][2] + bb.z, 0.f);
            v.w = fmaxf(acc[r][3] + bb.w, 0.f);
            *(float4*)&B[grow * 128 + tx * 4] = v;
        }
    }
}

// ---------- convert conv output fp32 -> bf16 frag-order tiles ----------
__global__ void k_tobf16(const float* __restrict__ C, u16* __restrict__ Xf) {
    int g = blockIdx.x * 256 + threadIdx.x;   // 0 .. 3,225,599
    int vr = g >> 5;                          // virtual row 0..100799
    int c4 = g & 31;
    int t = vr / 1008;
    int rv = vr - t * 1008;
    int r = min(rv, NPG - 1);
    int n = t * NPG + r;
    int col0 = c4 * 4;
    f32x4 v = *(const f32x4*)(C + (size_t)n * 128 + col0);
    u16 h0 = f2bf(v[0]), h1 = f2bf(v[1]), h2 = f2bf(v[2]), h3 = f2bf(v[3]);
    u64 pk = (u64)h0 | ((u64)h1 << 16) | ((u64)h2 << 32) | ((u64)h3 << 48);
    int rb = rv >> 4, rr = rv & 15;
    size_t idx = (size_t)(t * 63 + rb) * 2048
               + (size_t)((col0 >> 5) * 512 + ((col0 >> 3) & 3) * 128 + rr * 8 + (col0 & 7));
    *(u64*)(Xf + idx) = pk;
}

// ---------- LSTM weight prep ----------
__global__ void k_prepf(const float* __restrict__ Wih0, const float* __restrict__ Whh0,
                        const float* __restrict__ Wih1, const float* __restrict__ Whh1,
                        u16* __restrict__ WTf) {
    int idx = blockIdx.x * 256 + threadIdx.x;   // 0..32767
    int lane = idx & 63;
    int gt = (idx >> 6) & 3;
    int kt = (idx >> 8) & 7;
    int w  = (idx >> 11) & 7;
    int l  = idx >> 14;
    int d = 16 * w + (lane & 15);
    int k0 = kt * 32 + (lane >> 4) * 8;
    int wrow = gt * 128 + d;
    const float* Wi = l ? Wih1 : Wih0;
    const float* Wh = l ? Whh1 : Whh0;
    const float* srcp = (k0 < 128) ? (Wi + wrow * 128 + k0) : (Wh + wrow * 128 + (k0 - 128));
    u16 o[8];
#pragma unroll
    for (int j = 0; j < 8; ++j) o[j] = f2bf(srcp[j]);
    u64* dst = (u64*)(WTf + (size_t)idx * 8);
    dst[0] = (u64)o[0] | ((u64)o[1] << 16) | ((u64)o[2] << 32) | ((u64)o[3] << 48);
    dst[1] = (u64)o[4] | ((u64)o[5] << 16) | ((u64)o[6] << 32) | ((u64)o[7] << 48);
}

__global__ void k_bsum(const float* __restrict__ bih0, const float* __restrict__ bhh0,
                       const float* __restrict__ bih1, const float* __restrict__ bhh1,
                       float* __restrict__ bs) {
    int i = blockIdx.x * 256 + threadIdx.x; // 0..1023
    int l = i >> 9, c = i & 511;
    bs[i] = l ? (bih1[c] + bhh1[c]) : (bih0[c] + bhh0[c]);
}

// ---------- LSTM layer: register weights, pipelined x-MFMA, LDS-only barrier ----------
#define LSTM_STEP(ACC, ACCN, T, CUR)                                                   \
    do {                                                                               \
        BAR();                                                                         \
        _Pragma("unroll")                                                              \
        for (int kt = 0; kt < 4; ++kt) {                                               \
            bf16x8 af = *(const bf16x8*)(hsh[CUR] + kt * 512 + l * 8);                 \
            ACC[0] = MF(af, Bw[4 + kt][0], ACC[0]);                                    \
            ACC[1] = MF(af, Bw[4 + kt][1], ACC[1]);                                    \
            ACC[2] = MF(af, Bw[4 + kt][2], ACC[2]);                                    \
            ACC[3] = MF(af, Bw[4 + kt][3], ACC[3]);                                    \
        }                                                                              \
        if (mode == 0 && (T) > 0)                                                      \
            ((u64*)(Hout + (size_t)(((T) - 1) * 63 + rb) * 2048))[tid] =               \
                ((const u64*)hsh[CUR])[tid];                                           \
        if ((T) < 99) {                                                                \
            _Pragma("unroll")                                                          \
            for (int g = 0; g < 4; ++g) ACCN[g] = (f32x4){0.f, 0.f, 0.f, 0.f};         \
            _Pragma("unroll")                                                          \
            for (int kt = 0; kt < 4; ++kt) {                                           \
                ACCN[0] = MF(xf[kt], Bw[kt][0], ACCN[0]);                              \
                ACCN[1] = MF(xf[kt], Bw[kt][1], ACCN[1]);                              \
                ACCN[2] = MF(xf[kt], Bw[kt][2], ACCN[2]);                              \
                ACCN[3] = MF(xf[kt], Bw[kt][3], ACCN[3]);                              \
            }                                                                          \
        }                                                                              \
        if ((T) < 98) {                                                                \
            const u16* xn = xbase + (size_t)((T) + 2) * TSTR;                          \
            _Pragma("unroll")                                                          \
            for (int kt = 0; kt < 4; ++kt)                                             \
                xf[kt] = *(const bf16x8*)(xn + kt * 512);                              \
        }                                                                              \
        float hsum = 0.f;                                                              \
        _Pragma("unroll")                                                              \
        for (int reg = 0; reg < 4; ++reg) {                                            \
            float gi = ACC[0][reg] + bi;                                               \
            float gf = ACC[1][reg] + bf_;                                              \
            float gg = ACC[2][reg] + bg;                                               \
            float go = ACC[3][reg] + bo;                                               \
            float cprev = (reg == 0) ? cst0 : (reg == 1) ? cst1 : (reg == 2) ? cst2 : cst3; \
            float c = sigf(gf) * cprev + sigf(gi) * tanh_fast(gg);                     \
            if (reg == 0) cst0 = c; else if (reg == 1) cst1 = c;                       \
            else if (reg == 2) cst2 = c; else cst3 = c;                                \
            float h = sigf(go) * tanh_fast(c);                                         \
            hsh[(CUR) ^ 1][hbase + reg * 8] = f2bf(h);                                 \
            if (mode == 1) {                                                           \
                int row = (l >> 4) * 4 + reg;                                          \
                if (row < nreal) hsum += h;                                            \
            }                                                                          \
        }                                                                              \
        if (mode == 1) {                                                               \
            hsum += __shfl_xor(hsum, 16);                                              \
            hsum += __shfl_xor(hsum, 32);                                              \
            if ((l >> 4) == 0) atomicAdd(&pooled[(T) * 128 + d], hsum);                \
        }                                                                              \
    } while (0)

__global__ __launch_bounds__(512, 1)
void k_lstm_layer(const u16* __restrict__ Xf, const u16* __restrict__ WTl,
                  const float* __restrict__ bsL, u16* __restrict__ Hout,
                  float* __restrict__ pooled, int mode) {
    __shared__ __align__(16) u16 hsh[2][2048];
    int tid = threadIdx.x;
    int l = tid & 63;
    int w = tid >> 6;
    int rb = blockIdx.x;
    int n0 = rb * 16;
    int nreal = min(16, NPG - n0);

    bf16x8 Bw[8][4];
    const bf16x8* Wv = (const bf16x8*)WTl;
#pragma unroll
    for (int kt = 0; kt < 8; ++kt)
#pragma unroll
        for (int gt = 0; gt < 4; ++gt)
            Bw[kt][gt] = Wv[((w * 8 + kt) * 4 + gt) * 64 + l];

    int d = (w << 4) | (l & 15);
    float bi = bsL[d], bf_ = bsL[128 + d], bg = bsL[256 + d], bo = bsL[384 + d];
    float cst0 = 0.f, cst1 = 0.f, cst2 = 0.f, cst3 = 0.f;

    int ktp = d >> 5, oct = (d >> 3) & 3, boff = d & 7;
    int hbase = ktp * 512 + ((l >> 4) * 4 + 16 * oct) * 8 + boff;

    const u16* xbase = Xf + (size_t)rb * 2048 + l * 8;
    const size_t TSTR = (size_t)63 * 2048;

    // prologue: tile 0 -> accA x-part; prefetch tile 1
    bf16x8 xf[4];
#pragma unroll
    for (int kt = 0; kt < 4; ++kt) xf[kt] = *(const bf16x8*)(xbase + kt * 512);

    f32x4 accA[4], accB[4];
#pragma unroll
    for (int g = 0; g < 4; ++g) accA[g] = (f32x4){0.f, 0.f, 0.f, 0.f};
#pragma unroll
    for (int kt = 0; kt < 4; ++kt) {
        accA[0] = MF(xf[kt], Bw[kt][0], accA[0]);
        accA[1] = MF(xf[kt], Bw[kt][1], accA[1]);
        accA[2] = MF(xf[kt], Bw[kt][2], accA[2]);
        accA[3] = MF(xf[kt], Bw[kt][3], accA[3]);
    }
#pragma unroll
    for (int kt = 0; kt < 4; ++kt) xf[kt] = *(const bf16x8*)(xbase + TSTR + kt * 512);

    ((u64*)hsh[0])[tid] = 0ull;

    for (int t2 = 0; t2 < 50; ++t2) {
        int t0 = 2 * t2;
        LSTM_STEP(accA, accB, t0, 0);
        LSTM_STEP(accB, accA, t0 + 1, 1);
    }
    BAR();
    if (mode == 0)
        ((u64*)(Hout + (size_t)(99 * 63 + rb) * 2048))[tid] = ((const u64*)hsh[0])[tid];
}

// ---------- head ----------
__global__ void k_head(const float* __restrict__ pooled, const float* __restrict__ Wout,
                       const float* __restrict__ bout, float* __restrict__ out) {
    int gi = threadIdx.x;
    if (gi >= B_GR) return;
    float l0 = bout[0], l1 = bout[1];
    for (int d = 0; d < 128; ++d) {
        float p = pooled[gi * 128 + d] / 1000.0f;
        l0 += p * Wout[d * 2 + 0];
        l1 += p * Wout[d * 2 + 1];
    }
    float m = fmaxf(l0, l1);
    float lse = m + logf(__expf(l0 - m) + __expf(l1 - m));
    out[gi * 2 + 0] = l0 - lse;
    out[gi * 2 + 1] = l1 - lse;
}

// ---------- launch ----------
extern "C" void kernel_launch(void* const* d_in, const int* in_sizes, int n_in,
                              void* d_out, int out_size, void* d_ws, size_t ws_size,
                              hipStream_t stream) {
    const float* x    = (const float*)d_in[0];
    const int*   ei   = (const int*)d_in[1];
    const int*   srcI = ei;
    const int*   dstI = ei + E_EDGES;
    const float* Ws0  = (const float*)d_in[3];
    const float* Wn0  = (const float*)d_in[4];
    const float* b0   = (const float*)d_in[5];
    const float* Ws1  = (const float*)d_in[6];
    const float* Wn1  = (const float*)d_in[7];
    const float* b1   = (const float*)d_in[8];
    const float* Wih0 = (const float*)d_in[9];
    const float* Whh0 = (const float*)d_in[10];
    const float* bih0 = (const float*)d_in[11];
    const float* bhh0 = (const float*)d_in[12];
    const float* Wih1 = (const float*)d_in[13];
    const float* Whh1 = (const float*)d_in[14];
    const float* bih1 = (const float*)d_in[15];
    const float* bhh1 = (const float*)d_in[16];
    const float* Wout = (const float*)d_in[17];
    const float* bout = (const float*)d_in[18];
    float* out = (float*)d_out;

    char* ws = (char*)d_ws;
    int*   row_ptr = (int*)(ws + 0);            // (N+1) ints -> pad 400128
    int*   cursor  = (int*)(ws + 400128);       // N ints     -> 800128
    int*   csr_src = (int*)(ws + 800128);       // E ints     -> 7200128
    int*   bsum    = (int*)(ws + 7200128);      // 512B       -> 7200640
    u16*   Hbf     = (u16*)(ws + 7200640);      // N*128 bf16 -> 32800640 (reused later: Xf)
    float* bufB    = (float*)(ws + 58400640);   // N*128 f32  -> 109600640 (AG then conv1 out)
    u16*   WTf     = (u16*)(ws + 109600640);    // 2*256*512 bf16 -> 110124928
    float* bsB     = (float*)(ws + 110649216);  // 1024 f32   -> 110653312
    float* pooled  = (float*)(ws + 110653312);  // 100*128 f32-> 110704512

    // region reuse after conv1mm: Xf tiles (25.8MB) over Hbf; H0f tiles after
    u16* Xf  = (u16*)(ws + 7200640);
    u16* H0f = (u16*)(ws + 33005440);

    hipMemsetAsync(cursor, 0, N_NODES * sizeof(int), stream);
    hipMemsetAsync(pooled, 0, B_GR * 128 * sizeof(float), stream);

    k_count<<<E_EDGES / 256, 256, 0, stream>>>(dstI, cursor);
    k_scan1<<<98, 256, 0, stream>>>(cursor, row_ptr, bsum);
    k_scan2<<<1, 64, 0, stream>>>(bsum, 98);
    k_scan3<<<(N_NODES + 255) / 256, 256, 0, stream>>>(row_ptr, bsum, cursor);
    k_fill<<<E_EDGES / 256, 256, 0, stream>>>(srcI, dstI, cursor, csr_src);

    k_conv0<<<N_NODES, 128, 0, stream>>>(x, row_ptr, csr_src, Ws0, Wn0, b0, Hbf);
    k_agg2<<<N_NODES / 4, 256, 0, stream>>>(Hbf, row_ptr, csr_src, bufB);
    k_conv1mm<<<(N_NODES + 63) / 64, 256, 0, stream>>>(Hbf, bufB, Ws1, Wn1, b1);
    k_tobf16<<<12600, 256, 0, stream>>>(bufB, Xf);

    k_prepf<<<128, 256, 0, stream>>>(Wih0, Whh0, Wih1, Whh1, WTf);
    k_bsum<<<4, 256, 0, stream>>>(bih0, bhh0, bih1, bhh1, bsB);

    k_lstm_layer<<<63, 512, 0, stream>>>(Xf, WTf, bsB, H0f, nullptr, 0);
    k_lstm_layer<<<63, 512, 0, stream>>>(H0f, WTf + 131072, bsB + 512, nullptr, pooled, 1);

    k_head<<<1, 128, 0, stream>>>(pooled, Wout, bout, out);
}

// Round 8
// 828.231 us; speedup vs baseline: 2.5962x; 1.0122x over previous
//
#include <hip/hip_runtime.h>

#define N_NODES 100000
#define NPG     1000
#define B_GR    100
#define HDIM    128
#define E_EDGES 1600000

typedef __attribute__((ext_vector_type(8))) short bf16x8;
typedef __attribute__((ext_vector_type(4))) float f32x4;
typedef unsigned long long u64;
typedef unsigned short u16;

// ---------- helpers ----------
__device__ __forceinline__ float sigf(float x) { return 1.f / (1.f + __expf(-x)); }
__device__ __forceinline__ float tanh_fast(float x) { return 1.f - 2.f / (__expf(2.f * x) + 1.f); }
__device__ __forceinline__ u16 f2bf(float f) {
    unsigned u = __float_as_uint(f);
    unsigned r = (u + 0x7fffu + ((u >> 16) & 1u)) >> 16;
    return (u16)r;
}
__device__ __forceinline__ float bf2f(u16 h) { return __uint_as_float(((unsigned)h) << 16); }
__device__ __forceinline__ f32x4 MF(bf16x8 a, bf16x8 b, f32x4 c) {
    return __builtin_amdgcn_mfma_f32_16x16x32_bf16(a, b, c, 0, 0, 0);
}
// barrier that drains LDS ops only (no vmcnt(0) drain of global prefetch/stores)
#define BAR() asm volatile("s_waitcnt lgkmcnt(0)\n\ts_barrier" ::: "memory")

// ---------- CSR build ----------
__global__ void k_count(const int* __restrict__ dst, int* __restrict__ cnt) {
    int e = blockIdx.x * 256 + threadIdx.x;
    if (e < E_EDGES) atomicAdd(&cnt[dst[e]], 1);
}

__global__ void k_scan1(const int* __restrict__ cnt, int* __restrict__ row_ptr, int* __restrict__ bsum) {
    __shared__ int sd[256];
    int tid = threadIdx.x;
    int base = blockIdx.x * 1024 + tid * 4;
    int v[4];
#pragma unroll
    for (int j = 0; j < 4; ++j) {
        int i = base + j;
        v[j] = (i < N_NODES) ? cnt[i] : 0;
    }
    int s = v[0] + v[1] + v[2] + v[3];
    sd[tid] = s;
    __syncthreads();
    for (int off = 1; off < 256; off <<= 1) {
        int t = (tid >= off) ? sd[tid - off] : 0;
        __syncthreads();
        sd[tid] += t;
        __syncthreads();
    }
    int excl = sd[tid] - s;
    int run = excl;
#pragma unroll
    for (int j = 0; j < 4; ++j) {
        int i = base + j;
        run += v[j];
        if (i < N_NODES) row_ptr[1 + i] = run;
    }
    if (tid == 255) bsum[blockIdx.x] = sd[255];
}

__global__ void k_scan2(int* __restrict__ bsum, int nb) {
    if (threadIdx.x == 0 && blockIdx.x == 0) {
        int carry = 0;
        for (int b = 0; b < nb; ++b) {
            int t = bsum[b];
            bsum[b] = carry;
            carry += t;
        }
    }
}

__global__ void k_scan3(int* __restrict__ row_ptr, const int* __restrict__ bsum, int* __restrict__ cursor) {
    int i = blockIdx.x * 256 + threadIdx.x;
    if (i >= N_NODES) return;
    int incl = row_ptr[1 + i] + bsum[i >> 10];
    row_ptr[1 + i] = incl;
    if (i == 0) { row_ptr[0] = 0; cursor[0] = 0; }
    if (i + 1 < N_NODES) cursor[i + 1] = incl;
}

__global__ void k_fill(const int* __restrict__ src, const int* __restrict__ dst,
                       int* __restrict__ cursor, int* __restrict__ csr_src) {
    int e = blockIdx.x * 256 + threadIdx.x;
    if (e >= E_EDGES) return;
    int d = dst[e];
    int pos = atomicAdd(&cursor[d], 1);
    csr_src[pos] = src[e];
}

// ---------- conv layer 0: same structure as R5, output bf16 ----------
__global__ void k_conv0(const float* __restrict__ x, const int* __restrict__ rp, const int* __restrict__ csr,
                        const float* __restrict__ Ws, const float* __restrict__ Wn, const float* __restrict__ b,
                        u16* __restrict__ Hbf) {
    int n = blockIdx.x;
    int tid = threadIdx.x;
    __shared__ float sagg[3];
    if (tid < 3) sagg[tid] = 0.f;
    __syncthreads();
    int s0 = rp[n], s1 = rp[n + 1];
    int deg = s1 - s0;
    for (int j = tid; j < deg; j += 128) {
        int s = csr[s0 + j];
        atomicAdd(&sagg[0], x[s * 3 + 0]);
        atomicAdd(&sagg[1], x[s * 3 + 1]);
        atomicAdd(&sagg[2], x[s * 3 + 2]);
    }
    __syncthreads();
    float inv = 1.f / fmaxf((float)deg, 1.f);
    float a0 = sagg[0] * inv, a1 = sagg[1] * inv, a2 = sagg[2] * inv;
    float x0 = x[n * 3 + 0], x1 = x[n * 3 + 1], x2 = x[n * 3 + 2];
    float acc = b[tid]
        + x0 * Ws[0 * 128 + tid] + x1 * Ws[1 * 128 + tid] + x2 * Ws[2 * 128 + tid]
        + a0 * Wn[0 * 128 + tid] + a1 * Wn[1 * 128 + tid] + a2 * Wn[2 * 128 + tid];
    Hbf[(size_t)n * 128 + tid] = f2bf(fmaxf(acc, 0.f));
}

// ---------- agg2: wave per node, bf16 gather (u32 = 2 cols/lane), fp32 accumulate ----------
__global__ __launch_bounds__(256)
void k_agg2(const u16* __restrict__ hin, const int* __restrict__ rp, const int* __restrict__ csr,
            float* __restrict__ out) {
    int wid = threadIdx.x >> 6;
    int l = threadIdx.x & 63;
    int n = blockIdx.x * 4 + wid;
    if (n >= N_NODES) return;
    int s0 = rp[n], deg = rp[n + 1] - s0;
    float ax = 0.f, ay = 0.f;
    const unsigned* base = (const unsigned*)hin;   // 2 bf16 per u32; row = 64 u32
    for (int c0 = 0; c0 < deg; c0 += 64) {
        int m = min(64, deg - c0);
        int myidx = csr[s0 + c0 + ((l < m) ? l : 0)];
        int j = 0;
        for (; j + 4 <= m; j += 4) {
            int i0 = __shfl(myidx, j);
            int i1 = __shfl(myidx, j + 1);
            int i2 = __shfl(myidx, j + 2);
            int i3 = __shfl(myidx, j + 3);
            unsigned v0 = base[(size_t)i0 * 64 + l];
            unsigned v1 = base[(size_t)i1 * 64 + l];
            unsigned v2 = base[(size_t)i2 * 64 + l];
            unsigned v3 = base[(size_t)i3 * 64 + l];
            ax += bf2f((u16)v0); ay += bf2f((u16)(v0 >> 16));
            ax += bf2f((u16)v1); ay += bf2f((u16)(v1 >> 16));
            ax += bf2f((u16)v2); ay += bf2f((u16)(v2 >> 16));
            ax += bf2f((u16)v3); ay += bf2f((u16)(v3 >> 16));
        }
        for (; j < m; ++j) {
            int i0 = __shfl(myidx, j);
            unsigned v = base[(size_t)i0 * 64 + l];
            ax += bf2f((u16)v); ay += bf2f((u16)(v >> 16));
        }
    }
    float dv = fmaxf((float)deg, 1.f);
    float2 o; o.x = ax / dv; o.y = ay / dv;
    *(float2*)&out[(size_t)n * 128 + l * 2] = o;
}

// ---------- conv layer 1 transform: B <- relu(A@Wself + B@Wnbr + bias); A from bf16 Hbf ----------
__global__ __launch_bounds__(256)
void k_conv1mm(const u16* __restrict__ Hbf, float* __restrict__ B,
               const float* __restrict__ Wself, const float* __restrict__ Wnbr,
               const float* __restrict__ bias) {
    __shared__ float As[64 * 64];
    __shared__ float Wls[64 * 128];
    int tid = threadIdx.x;
    int r0 = blockIdx.x * 64;
    int tx = tid & 31, ty = tid >> 5;
    float acc[8][4];
#pragma unroll
    for (int r = 0; r < 8; ++r)
#pragma unroll
        for (int j = 0; j < 4; ++j) acc[r][j] = 0.f;

    for (int chunk = 0; chunk < 4; ++chunk) {
        const float* Wsrc = (chunk < 2) ? Wself : Wnbr;
        int k0 = (chunk & 1) * 64;
#pragma unroll
        for (int i = 0; i < 4; ++i) {
            int e = tid + 256 * i;
            int row = e >> 4, c4 = e & 15;
            int grow = r0 + row;
            float4 v = make_float4(0.f, 0.f, 0.f, 0.f);
            if (grow < N_NODES) {
                if (chunk < 2) {
                    u64 p = *(const u64*)&Hbf[(size_t)grow * 128 + k0 + c4 * 4];
                    v.x = bf2f((u16)p);         v.y = bf2f((u16)(p >> 16));
                    v.z = bf2f((u16)(p >> 32)); v.w = bf2f((u16)(p >> 48));
                } else {
                    v = *(const float4*)&B[(size_t)grow * 128 + k0 + c4 * 4];
                }
            }
            *(float4*)&As[row * 64 + c4 * 4] = v;
        }
#pragma unroll
        for (int i = 0; i < 8; ++i) {
            int e = tid + 256 * i;
            int row = e >> 5, c4 = e & 31;
            *(float4*)&Wls[row * 128 + c4 * 4] = *(const float4*)&Wsrc[(k0 + row) * 128 + c4 * 4];
        }
        __syncthreads();
#pragma unroll 4
        for (int kk = 0; kk < 64; ++kk) {
            float4 w = *(const float4*)&Wls[kk * 128 + tx * 4];
#pragma unroll
            for (int r = 0; r < 8; ++r) {
                float a = As[(ty + 8 * r) * 64 + kk];
                acc[r][0] += a * w.x; acc[r][1] += a * w.y;
                acc[r][2] += a * w.z; acc[r][3] += a * w.w;
            }
        }
        __syncthreads();
    }
    float4 bb = *(const float4*)&bias[tx * 4];
#pragma unroll
    for (int r = 0; r < 8; ++r) {
        int grow = r0 + ty + 8 * r;
        if (grow < N_NODES) {
            float4 v;
            v.x = fmaxf(acc[r][0] + bb.x, 0.f);
            v.y = fmaxf(acc[r][1] + bb.y, 0.f);
            v.z = fmaxf(acc[r][2] + bb.z, 0.f);
            v.w = fmaxf(acc[r][3] + bb.w, 0.f);
            *(float4*)&B[grow * 128 + tx * 4] = v;
        }
    }
}

// ---------- convert conv output fp32 -> bf16 frag-order tiles ----------
__global__ void k_tobf16(const float* __restrict__ C, u16* __restrict__ Xf) {
    int g = blockIdx.x * 256 + threadIdx.x;   // 0 .. 3,225,599
    int vr = g >> 5;                          // virtual row 0..100799
    int c4 = g & 31;
    int t = vr / 1008;
    int rv = vr - t * 1008;
    int r = min(rv, NPG - 1);
    int n = t * NPG + r;
    int col0 = c4 * 4;
    f32x4 v = *(const f32x4*)(C + (size_t)n * 128 + col0);
    u16 h0 = f2bf(v[0]), h1 = f2bf(v[1]), h2 = f2bf(v[2]), h3 = f2bf(v[3]);
    u64 pk = (u64)h0 | ((u64)h1 << 16) | ((u64)h2 << 32) | ((u64)h3 << 48);
    int rb = rv >> 4, rr = rv & 15;
    size_t idx = (size_t)(t * 63 + rb) * 2048
               + (size_t)((col0 >> 5) * 512 + ((col0 >> 3) & 3) * 128 + rr * 8 + (col0 & 7));
    *(u64*)(Xf + idx) = pk;
}

// ---------- LSTM weight prep ----------
__global__ void k_prepf(const float* __restrict__ Wih0, const float* __restrict__ Whh0,
                        const float* __restrict__ Wih1, const float* __restrict__ Whh1,
                        u16* __restrict__ WTf) {
    int idx = blockIdx.x * 256 + threadIdx.x;   // 0..32767
    int lane = idx & 63;
    int gt = (idx >> 6) & 3;
    int kt = (idx >> 8) & 7;
    int w  = (idx >> 11) & 7;
    int l  = idx >> 14;
    int d = 16 * w + (lane & 15);
    int k0 = kt * 32 + (lane >> 4) * 8;
    int wrow = gt * 128 + d;
    const float* Wi = l ? Wih1 : Wih0;
    const float* Wh = l ? Whh1 : Whh0;
    const float* srcp = (k0 < 128) ? (Wi + wrow * 128 + k0) : (Wh + wrow * 128 + (k0 - 128));
    u16 o[8];
#pragma unroll
    for (int j = 0; j < 8; ++j) o[j] = f2bf(srcp[j]);
    u64* dst = (u64*)(WTf + (size_t)idx * 8);
    dst[0] = (u64)o[0] | ((u64)o[1] << 16) | ((u64)o[2] << 32) | ((u64)o[3] << 48);
    dst[1] = (u64)o[4] | ((u64)o[5] << 16) | ((u64)o[6] << 32) | ((u64)o[7] << 48);
}

__global__ void k_bsum(const float* __restrict__ bih0, const float* __restrict__ bhh0,
                       const float* __restrict__ bih1, const float* __restrict__ bhh1,
                       float* __restrict__ bs) {
    int i = blockIdx.x * 256 + threadIdx.x; // 0..1023
    int l = i >> 9, c = i & 511;
    bs[i] = l ? (bih1[c] + bhh1[c]) : (bih0[c] + bhh0[c]);
}

// ---------- LSTM layer: register weights (asm-pinned), pipelined x-MFMA, LDS-only barrier ----------
#define LSTM_STEP(ACC, ACCN, T, CUR)                                                   \
    do {                                                                               \
        BAR();                                                                         \
        _Pragma("unroll")                                                              \
        for (int kt = 0; kt < 4; ++kt) {                                               \
            bf16x8 af = *(const bf16x8*)(hsh[CUR] + kt * 512 + l * 8);                 \
            ACC[0] = MF(af, Bw[4 + kt][0], ACC[0]);                                    \
            ACC[1] = MF(af, Bw[4 + kt][1], ACC[1]);                                    \
            ACC[2] = MF(af, Bw[4 + kt][2], ACC[2]);                                    \
            ACC[3] = MF(af, Bw[4 + kt][3], ACC[3]);                                    \
        }                                                                              \
        if (mode == 0 && (T) > 0)                                                      \
            ((u64*)(Hout + (size_t)(((T) - 1) * 63 + rb) * 2048))[tid] =               \
                ((const u64*)hsh[CUR])[tid];                                           \
        if ((T) < 99) {                                                                \
            _Pragma("unroll")                                                          \
            for (int g = 0; g < 4; ++g) ACCN[g] = (f32x4){0.f, 0.f, 0.f, 0.f};         \
            _Pragma("unroll")                                                          \
            for (int kt = 0; kt < 4; ++kt) {                                           \
                ACCN[0] = MF(xf[kt], Bw[kt][0], ACCN[0]);                              \
                ACCN[1] = MF(xf[kt], Bw[kt][1], ACCN[1]);                              \
                ACCN[2] = MF(xf[kt], Bw[kt][2], ACCN[2]);                              \
                ACCN[3] = MF(xf[kt], Bw[kt][3], ACCN[3]);                              \
            }                                                                          \
        }                                                                              \
        if ((T) < 98) {                                                                \
            const u16* xn = xbase + (size_t)((T) + 2) * TSTR;                          \
            _Pragma("unroll")                                                          \
            for (int kt = 0; kt < 4; ++kt)                                             \
                xf[kt] = *(const bf16x8*)(xn + kt * 512);                              \
        }                                                                              \
        float hsum = 0.f;                                                              \
        _Pragma("unroll")                                                              \
        for (int reg = 0; reg < 4; ++reg) {                                            \
            float gi = ACC[0][reg] + bi;                                               \
            float gf = ACC[1][reg] + bf_;                                              \
            float gg = ACC[2][reg] + bg;                                               \
            float go = ACC[3][reg] + bo;                                               \
            float cprev = (reg == 0) ? cst0 : (reg == 1) ? cst1 : (reg == 2) ? cst2 : cst3; \
            float c = sigf(gf) * cprev + sigf(gi) * tanh_fast(gg);                     \
            if (reg == 0) cst0 = c; else if (reg == 1) cst1 = c;                       \
            else if (reg == 2) cst2 = c; else cst3 = c;                                \
            float h = sigf(go) * tanh_fast(c);                                         \
            hsh[(CUR) ^ 1][hbase + reg * 8] = f2bf(h);                                 \
            if (mode == 1) {                                                           \
                int row = (l >> 4) * 4 + reg;                                          \
                if (row < nreal) hsum += h;                                            \
            }                                                                          \
        }                                                                              \
        if (mode == 1) {                                                               \
            hsum += __shfl_xor(hsum, 16);                                              \
            hsum += __shfl_xor(hsum, 32);                                              \
            if ((l >> 4) == 0) atomicAdd(&pooled[(T) * 128 + d], hsum);                \
        }                                                                              \
    } while (0)

__global__ __launch_bounds__(512, 1)
void k_lstm_layer(const u16* __restrict__ Xf, const u16* __restrict__ WTl,
                  const float* __restrict__ bsL, u16* __restrict__ Hout,
                  float* __restrict__ pooled, int mode) {
    __shared__ __align__(16) u16 hsh[2][2048];
    int tid = threadIdx.x;
    int l = tid & 63;
    int w = tid >> 6;
    int rb = blockIdx.x;
    int n0 = rb * 16;
    int nreal = min(16, NPG - n0);

    // preload this wave's 32 B-fragments, then PIN them: the empty asm with a
    // read-write "v" constraint makes each value opaque -- the compiler cannot
    // rematerialize the global load inside the t-loop (the R7 failure mode:
    // 256KB/step re-streamed from L2 = the whole 4680cyc step time).
    bf16x8 Bw[8][4];
    const bf16x8* Wv = (const bf16x8*)WTl;
#pragma unroll
    for (int kt = 0; kt < 8; ++kt)
#pragma unroll
        for (int gt = 0; gt < 4; ++gt)
            Bw[kt][gt] = Wv[((w * 8 + kt) * 4 + gt) * 64 + l];
#pragma unroll
    for (int kt = 0; kt < 8; ++kt)
#pragma unroll
        for (int gt = 0; gt < 4; ++gt)
            asm volatile("" : "+v"(Bw[kt][gt]));

    int d = (w << 4) | (l & 15);
    float bi = bsL[d], bf_ = bsL[128 + d], bg = bsL[256 + d], bo = bsL[384 + d];
    float cst0 = 0.f, cst1 = 0.f, cst2 = 0.f, cst3 = 0.f;

    int ktp = d >> 5, oct = (d >> 3) & 3, boff = d & 7;
    int hbase = ktp * 512 + ((l >> 4) * 4 + 16 * oct) * 8 + boff;

    const u16* xbase = Xf + (size_t)rb * 2048 + l * 8;
    const size_t TSTR = (size_t)63 * 2048;

    // prologue: tile 0 -> accA x-part; prefetch tile 1
    bf16x8 xf[4];
#pragma unroll
    for (int kt = 0; kt < 4; ++kt) xf[kt] = *(const bf16x8*)(xbase + kt * 512);

    f32x4 accA[4], accB[4];
#pragma unroll
    for (int g = 0; g < 4; ++g) accA[g] = (f32x4){0.f, 0.f, 0.f, 0.f};
#pragma unroll
    for (int kt = 0; kt < 4; ++kt) {
        accA[0] = MF(xf[kt], Bw[kt][0], accA[0]);
        accA[1] = MF(xf[kt], Bw[kt][1], accA[1]);
        accA[2] = MF(xf[kt], Bw[kt][2], accA[2]);
        accA[3] = MF(xf[kt], Bw[kt][3], accA[3]);
    }
#pragma unroll
    for (int kt = 0; kt < 4; ++kt) xf[kt] = *(const bf16x8*)(xbase + TSTR + kt * 512);

    ((u64*)hsh[0])[tid] = 0ull;

    for (int t2 = 0; t2 < 50; ++t2) {
        int t0 = 2 * t2;
        LSTM_STEP(accA, accB, t0, 0);
        LSTM_STEP(accB, accA, t0 + 1, 1);
    }
    BAR();
    if (mode == 0)
        ((u64*)(Hout + (size_t)(99 * 63 + rb) * 2048))[tid] = ((const u64*)hsh[0])[tid];
}

// ---------- head ----------
__global__ void k_head(const float* __restrict__ pooled, const float* __restrict__ Wout,
                       const float* __restrict__ bout, float* __restrict__ out) {
    int gi = threadIdx.x;
    if (gi >= B_GR) return;
    float l0 = bout[0], l1 = bout[1];
    for (int d = 0; d < 128; ++d) {
        float p = pooled[gi * 128 + d] / 1000.0f;
        l0 += p * Wout[d * 2 + 0];
        l1 += p * Wout[d * 2 + 1];
    }
    float m = fmaxf(l0, l1);
    float lse = m + logf(__expf(l0 - m) + __expf(l1 - m));
    out[gi * 2 + 0] = l0 - lse;
    out[gi * 2 + 1] = l1 - lse;
}

// ---------- launch ----------
extern "C" void kernel_launch(void* const* d_in, const int* in_sizes, int n_in,
                              void* d_out, int out_size, void* d_ws, size_t ws_size,
                              hipStream_t stream) {
    const float* x    = (const float*)d_in[0];
    const int*   ei   = (const int*)d_in[1];
    const int*   srcI = ei;
    const int*   dstI = ei + E_EDGES;
    const float* Ws0  = (const float*)d_in[3];
    const float* Wn0  = (const float*)d_in[4];
    const float* b0   = (const float*)d_in[5];
    const float* Ws1  = (const float*)d_in[6];
    const float* Wn1  = (const float*)d_in[7];
    const float* b1   = (const float*)d_in[8];
    const float* Wih0 = (const float*)d_in[9];
    const float* Whh0 = (const float*)d_in[10];
    const float* bih0 = (const float*)d_in[11];
    const float* bhh0 = (const float*)d_in[12];
    const float* Wih1 = (const float*)d_in[13];
    const float* Whh1 = (const float*)d_in[14];
    const float* bih1 = (const float*)d_in[15];
    const float* bhh1 = (const float*)d_in[16];
    const float* Wout = (const float*)d_in[17];
    const float* bout = (const float*)d_in[18];
    float* out = (float*)d_out;

    char* ws = (char*)d_ws;
    int*   row_ptr = (int*)(ws + 0);            // (N+1) ints -> pad 400128
    int*   cursor  = (int*)(ws + 400128);       // N ints     -> 800128
    int*   csr_src = (int*)(ws + 800128);       // E ints     -> 7200128
    int*   bsum    = (int*)(ws + 7200128);      // 512B       -> 7200640
    u16*   Hbf     = (u16*)(ws + 7200640);      // N*128 bf16 -> 32800640 (reused later: Xf)
    float* bufB    = (float*)(ws + 58400640);   // N*128 f32  -> 109600640 (AG then conv1 out)
    u16*   WTf     = (u16*)(ws + 109600640);    // 2*256*512 bf16 -> 110124928
    float* bsB     = (float*)(ws + 110649216);  // 1024 f32   -> 110653312
    float* pooled  = (float*)(ws + 110653312);  // 100*128 f32-> 110704512

    // region reuse after conv1mm: Xf tiles (25.8MB) over Hbf; H0f tiles after
    u16* Xf  = (u16*)(ws + 7200640);
    u16* H0f = (u16*)(ws + 33005440);

    hipMemsetAsync(cursor, 0, N_NODES * sizeof(int), stream);
    hipMemsetAsync(pooled, 0, B_GR * 128 * sizeof(float), stream);

    k_count<<<E_EDGES / 256, 256, 0, stream>>>(dstI, cursor);
    k_scan1<<<98, 256, 0, stream>>>(cursor, row_ptr, bsum);
    k_scan2<<<1, 64, 0, stream>>>(bsum, 98);
    k_scan3<<<(N_NODES + 255) / 256, 256, 0, stream>>>(row_ptr, bsum, cursor);
    k_fill<<<E_EDGES / 256, 256, 0, stream>>>(srcI, dstI, cursor, csr_src);

    k_conv0<<<N_NODES, 128, 0, stream>>>(x, row_ptr, csr_src, Ws0, Wn0, b0, Hbf);
    k_agg2<<<N_NODES / 4, 256, 0, stream>>>(Hbf, row_ptr, csr_src, bufB);
    k_conv1mm<<<(N_NODES + 63) / 64, 256, 0, stream>>>(Hbf, bufB, Ws1, Wn1, b1);
    k_tobf16<<<12600, 256, 0, stream>>>(bufB, Xf);

    k_prepf<<<128, 256, 0, stream>>>(Wih0, Whh0, Wih1, Whh1, WTf);
    k_bsum<<<4, 256, 0, stream>>>(bih0, bhh0, bih1, bhh1, bsB);

    k_lstm_layer<<<63, 512, 0, stream>>>(Xf, WTf, bsB, H0f, nullptr, 0);
    k_lstm_layer<<<63, 512, 0, stream>>>(H0f, WTf + 131072, bsB + 512, nullptr, pooled, 1);

    k_head<<<1, 128, 0, stream>>>(pooled, Wout, bout, out);
}